// Round 6
// baseline (297.208 us; speedup 1.0000x reference)
//
#include <hip/hip_runtime.h>
#include <math.h>

// x [2,64,16,64,64], y [2,128,8,32,32]
// w_down_h [64,128], w_down_l [64,64], w_flow [3,128,3,3,3],
// w_att_atten [64,64], w_att_conv [64,64]
// out = grid_sample(y, vgrid) -> [2,128,16,64,64] fp32

// ---------------- kernel A: per-channel mean of x ----------------
__global__ void kmean(const float* __restrict__ x, float* __restrict__ meanx) {
    int ch = blockIdx.x;  // 0..127  (n*64+c)
    const float4* base = (const float4*)(x + (size_t)ch * 65536);
    float s = 0.f;
    for (int j = threadIdx.x; j < 16384; j += 256) {
        float4 v = base[j];
        s += v.x + v.y + v.z + v.w;
    }
    __shared__ float red[256];
    red[threadIdx.x] = s;
    __syncthreads();
    for (int off = 128; off > 0; off >>= 1) {
        if (threadIdx.x < off) red[threadIdx.x] += red[threadIdx.x + off];
        __syncthreads();
    }
    if (threadIdx.x == 0) meanx[ch] = red[0] * (1.0f / 65536.0f);
}

// ---------------- kernel B: build W_comb^T per batch ----------------
__global__ void kprep(const float* __restrict__ wdl, const float* __restrict__ watt,
                      const float* __restrict__ wconv, const float* __restrict__ meanx,
                      float* __restrict__ wcombT) {
    int n = blockIdx.x;
    int c = threadIdx.x;  // 64 threads
    __shared__ float pooled[64], sc[64];
    float p = 0.f;
    for (int i = 0; i < 64; ++i) p += wdl[c * 64 + i] * meanx[n * 64 + i];
    pooled[c] = p;
    __syncthreads();
    float a = 0.f;
    for (int i = 0; i < 64; ++i) a += watt[c * 64 + i] * pooled[i];
    sc[c] = 1.f + 1.f / (1.f + expf(-a));
    __syncthreads();
    int o = c;
    for (int i = 0; i < 64; ++i) {
        float acc = 0.f;
        for (int j = 0; j < 64; ++j) acc += wconv[o * 64 + j] * sc[j] * wdl[j * 64 + i];
        wcombT[n * 4096 + i * 64 + o] = acc;
    }
}

// ---------------- kernel C: low2 = W_comb * x ----------------
__global__ __launch_bounds__(256) void kconv1l(const float* __restrict__ x,
                                               const float* __restrict__ wcombT,
                                               float* __restrict__ low2) {
    int b = blockIdx.x;  // 512
    int n = b >> 8, tile = b & 255;
    __shared__ float4 Wl[1024];
    const float4* src = (const float4*)(wcombT + n * 4096);
    for (int k = threadIdx.x; k < 1024; k += 256) Wl[k] = src[k];
    __syncthreads();
    int p = tile * 256 + threadIdx.x;
    float4 acc[16];
#pragma unroll
    for (int o = 0; o < 16; ++o) acc[o] = make_float4(0.f, 0.f, 0.f, 0.f);
    const float* xb = x + (size_t)n * 64 * 65536 + p;
    for (int i = 0; i < 64; ++i) {
        float xi = xb[(size_t)i * 65536];
#pragma unroll
        for (int o = 0; o < 16; ++o) {
            float4 w = Wl[i * 16 + o];
            acc[o].x = fmaf(w.x, xi, acc[o].x);
            acc[o].y = fmaf(w.y, xi, acc[o].y);
            acc[o].z = fmaf(w.z, xi, acc[o].z);
            acc[o].w = fmaf(w.w, xi, acc[o].w);
        }
    }
    float* ob = low2 + (size_t)n * 64 * 65536 + p;
#pragma unroll
    for (int o = 0; o < 16; ++o) {
        ob[(size_t)(4 * o + 0) * 65536] = acc[o].x;
        ob[(size_t)(4 * o + 1) * 65536] = acc[o].y;
        ob[(size_t)(4 * o + 2) * 65536] = acc[o].z;
        ob[(size_t)(4 * o + 3) * 65536] = acc[o].w;
    }
}

// ---------------- kernel D: hf = w_down_h * y ----------------
__global__ __launch_bounds__(256) void kconvh(const float* __restrict__ y,
                                              const float* __restrict__ wdh,
                                              float* __restrict__ hf) {
    int b = blockIdx.x;  // 64
    int n = b >> 5, tile = b & 31;
    __shared__ float Wh[8192];
    for (int k = threadIdx.x; k < 8192; k += 256) {
        int i = k >> 6, o = k & 63;
        Wh[k] = wdh[o * 128 + i];
    }
    __syncthreads();
    int p = tile * 256 + threadIdx.x;
    float4 acc[16];
#pragma unroll
    for (int o = 0; o < 16; ++o) acc[o] = make_float4(0.f, 0.f, 0.f, 0.f);
    const float* yb = y + (size_t)n * 128 * 8192 + p;
    const float4* Wh4 = (const float4*)Wh;
    for (int i = 0; i < 128; ++i) {
        float yi = yb[(size_t)i * 8192];
#pragma unroll
        for (int o = 0; o < 16; ++o) {
            float4 w = Wh4[i * 16 + o];
            acc[o].x = fmaf(w.x, yi, acc[o].x);
            acc[o].y = fmaf(w.y, yi, acc[o].y);
            acc[o].z = fmaf(w.z, yi, acc[o].z);
            acc[o].w = fmaf(w.w, yi, acc[o].w);
        }
    }
    float* ob = hf + (size_t)n * 64 * 8192 + p;
#pragma unroll
    for (int o = 0; o < 16; ++o) {
        ob[(size_t)(4 * o + 0) * 8192] = acc[o].x;
        ob[(size_t)(4 * o + 1) * 8192] = acc[o].y;
        ob[(size_t)(4 * o + 2) * 8192] = acc[o].z;
        ob[(size_t)(4 * o + 3) * 8192] = acc[o].w;
    }
}

// ---------------- kernel E: trilinear upsample (align_corners=True) ----------------
__global__ void kups(const float* __restrict__ hf, float* __restrict__ hfup) {
    int idx = blockIdx.x * 256 + threadIdx.x;  // 8388608 total
    int w = idx & 63, h = (idx >> 6) & 63, d = (idx >> 12) & 15;
    int c = (idx >> 16) & 63, n = idx >> 22;
    const float SD = 7.0f / 15.0f, SH = 31.0f / 63.0f;
    float pd = (float)d * SD, ph = (float)h * SH, pw = (float)w * SH;
    int z0 = (int)pd; if (z0 > 7) z0 = 7;
    int z1 = min(z0 + 1, 7); float fz = pd - (float)z0;
    int y0 = (int)ph; if (y0 > 31) y0 = 31;
    int y1 = min(y0 + 1, 31); float fy = ph - (float)y0;
    int x0 = (int)pw; if (x0 > 31) x0 = 31;
    int x1 = min(x0 + 1, 31); float fx = pw - (float)x0;
    const float* b = hf + (size_t)(n * 64 + c) * 8192;
    float v000 = b[(z0 * 32 + y0) * 32 + x0], v001 = b[(z0 * 32 + y0) * 32 + x1];
    float v010 = b[(z0 * 32 + y1) * 32 + x0], v011 = b[(z0 * 32 + y1) * 32 + x1];
    float v100 = b[(z1 * 32 + y0) * 32 + x0], v101 = b[(z1 * 32 + y0) * 32 + x1];
    float v110 = b[(z1 * 32 + y1) * 32 + x0], v111 = b[(z1 * 32 + y1) * 32 + x1];
    float c00 = v000 + (v001 - v000) * fx;
    float c01 = v010 + (v011 - v010) * fx;
    float c10 = v100 + (v101 - v100) * fx;
    float c11 = v110 + (v111 - v110) * fx;
    float c0 = c00 + (c01 - c00) * fy;
    float c1 = c10 + (c11 - c10) * fy;
    hfup[idx] = c0 + (c1 - c0) * fz;
}

// ---------------- kernel F: 3x3x3 conv partials, LDS-free, register-blocked ----------------
// Tile 4z x 16y x 32x per block; thread = (xo:4, ty:16, tz:4), 8 x-outputs x 3 flow ch.
// Tap re-reads hit L1 (per-block per-ch window ~15 KB). Weights are block-uniform s_loads.
// part layout unchanged: part[((split*2 + n)*3 + o)*65536 + p], 16 splits.
__global__ __launch_bounds__(256, 4) void kflowp(const float* __restrict__ hfup,
                                                 const float* __restrict__ low2,
                                                 const float* __restrict__ wflow,
                                                 float* __restrict__ part) {
    const int b = blockIdx.x;          // 1024
    const int split = b & 15;          // 8 channels each
    const int tile = b >> 4;           // 0..63
    const int n = tile >> 5;
    const int t = tile & 31;           // td(2) th(2) tw(1)
    const int td = t >> 3, th = (t >> 1) & 3, tw = t & 1;
    const int d0 = td * 4, h0 = th * 16, w0 = tw * 32;
    const int tid = threadIdx.x;
    const int xo = tid & 3, ty = (tid >> 2) & 15, tz = tid >> 6;
    const int oz = d0 + tz, oy = h0 + ty, ox = w0 + 8 * xo;

    float acc[3][8];
#pragma unroll
    for (int o = 0; o < 3; ++o)
#pragma unroll
        for (int j = 0; j < 8; ++j) acc[o][j] = 0.f;

    const bool v0ok = (ox - 1) >= 0;
    const bool v9ok = (ox + 8) <= 63;
    const int xL = v0ok ? (ox - 1) : 0;
    const int xR = v9ok ? (ox + 8) : 63;

    for (int ci = 0; ci < 8; ++ci) {
        const int cg = split * 8 + ci;
        const float* src = (cg < 64) ? hfup + (size_t)(n * 64 + cg) * 65536
                                     : low2 + (size_t)(n * 64 + cg - 64) * 65536;
        const float* wb = wflow + cg * 27;   // + o*3456 + tap (block-uniform)
#pragma unroll
        for (int dz = 0; dz < 3; ++dz) {
            const int gz = oz + dz - 1;
            if ((unsigned)gz < 16u) {
#pragma unroll
                for (int dy = 0; dy < 3; ++dy) {
                    const int gy = oy + dy - 1;
                    const bool yok = (unsigned)gy < 64u;   // folds to true for dy==1
                    const int gyc = min(max(gy, 0), 63);
                    const float* rp = src + gz * 4096 + gyc * 64;
                    const float4 va = *(const float4*)(rp + ox);
                    const float4 vb = *(const float4*)(rp + ox + 4);
                    const float eL = rp[xL];
                    const float eR = rp[xR];
                    float v[10];
                    v[0] = (v0ok && yok) ? eL : 0.f;
                    v[1] = yok ? va.x : 0.f;
                    v[2] = yok ? va.y : 0.f;
                    v[3] = yok ? va.z : 0.f;
                    v[4] = yok ? va.w : 0.f;
                    v[5] = yok ? vb.x : 0.f;
                    v[6] = yok ? vb.y : 0.f;
                    v[7] = yok ? vb.z : 0.f;
                    v[8] = yok ? vb.w : 0.f;
                    v[9] = (v9ok && yok) ? eR : 0.f;
                    float wq[3][3];
#pragma unroll
                    for (int o = 0; o < 3; ++o)
#pragma unroll
                        for (int dx = 0; dx < 3; ++dx)
                            wq[o][dx] = wb[o * 3456 + (dz * 3 + dy) * 3 + dx];
#pragma unroll
                    for (int o = 0; o < 3; ++o)
#pragma unroll
                        for (int j = 0; j < 8; ++j)
#pragma unroll
                            for (int dx = 0; dx < 3; ++dx)
                                acc[o][j] = fmaf(wq[o][dx], v[j + dx], acc[o][j]);
                }
            }
        }
    }

    const size_t base = ((size_t)(split * 2 + n)) * 3 * 65536;
    const int p = oz * 4096 + oy * 64 + ox;
#pragma unroll
    for (int o = 0; o < 3; ++o) {
        float* pp = part + base + (size_t)o * 65536 + p;
        *(float4*)(pp)     = make_float4(acc[o][0], acc[o][1], acc[o][2], acc[o][3]);
        *(float4*)(pp + 4) = make_float4(acc[o][4], acc[o][5], acc[o][6], acc[o][7]);
    }
}

// ---------------- kernel F2: combine partials + grid + normalize -> vgrid ----------------
__global__ void kcomb(const float* __restrict__ part, float* __restrict__ vg) {
    int gid = blockIdx.x * 256 + threadIdx.x;  // 131072
    int n = gid >> 16, p = gid & 65535;
    float s0 = 0.f, s1 = 0.f, s2 = 0.f;
    for (int s = 0; s < 16; ++s) {
        const float* bp = part + ((size_t)(s * 2 + n)) * 3 * 65536 + p;
        s0 += bp[0];
        s1 += bp[65536];
        s2 += bp[131072];
    }
    int w = p & 63, h = (p >> 6) & 63, d = p >> 12;
    size_t vb = (size_t)n * 3 * 65536;
    vg[vb + p]          = ((float)w + s0) * (1.0f / 64.0f);
    vg[vb + 65536 + p]  = ((float)h + s1) * (1.0f / 64.0f);
    vg[vb + 131072 + p] = ((float)d + s2) * (1.0f / 16.0f);
}

// ---------------- kernel T: transpose y -> channel-last yt [n][8192][128] ----------------
__global__ __launch_bounds__(256) void ktrans(const float* __restrict__ y,
                                              float* __restrict__ yt) {
    int b = blockIdx.x;       // 512
    int n = b >> 8;
    int rem = b & 255;        // 2 c-tiles * 128 s-tiles
    int ct = rem >> 7, st = rem & 127;
    int c0 = ct * 64, s0 = st * 64;
    __shared__ float t[64][65];
    int tx = threadIdx.x & 63, ty = threadIdx.x >> 6;  // 4 rows/pass
#pragma unroll
    for (int k = 0; k < 16; ++k)
        t[ty + 4 * k][tx] = y[((size_t)(n * 128 + c0 + ty + 4 * k)) * 8192 + s0 + tx];
    __syncthreads();
#pragma unroll
    for (int k = 0; k < 16; ++k)
        yt[((size_t)(n * 8192 + s0 + ty + 4 * k)) * 128 + c0 + tx] = t[tx][ty + 4 * k];
}

// ---------------- kernel G: grid_sample, channel-last gathers ----------------
__global__ __launch_bounds__(256) void ksample(const float* __restrict__ yt,
                                               const float* __restrict__ vg,
                                               float* __restrict__ out) {
    const int b = blockIdx.x;        // 2048
    const int n = b >> 10;
    const int p0 = (b & 1023) << 6;  // 64 points per block
    const int tid = threadIdx.x;
    const int lane = tid & 63;
    const int wv = tid >> 6;         // 0..3

    __shared__ float lds[128 * 65];  // [c][pt], pad 65

    const float* ytn = yt + (size_t)n * 8192 * 128;
    const size_t vb = (size_t)n * 3 * 65536;

    for (int q = 0; q < 16; ++q) {
        const int pt = wv * 16 + q;  // 0..63, wave-uniform
        const int p = p0 + pt;
        float gx = vg[vb + p], gy = vg[vb + 65536 + p], gz = vg[vb + 131072 + p];
        float ix = ((gx + 1.f) * 32.f - 1.f) * 0.5f;
        float iy = ((gy + 1.f) * 32.f - 1.f) * 0.5f;
        float iz = ((gz + 1.f) * 8.f - 1.f) * 0.5f;
        int x0 = (int)floorf(ix), y0 = (int)floorf(iy), z0 = (int)floorf(iz);
        float fx = ix - (float)x0, fy = iy - (float)y0, fz = iz - (float)z0;
        float wx[2] = {1.f - fx, fx}, wy[2] = {1.f - fy, fy}, wz[2] = {1.f - fz, fz};
        int idx8[8];
        float w8[8];
        float wsum = 0.f;
#pragma unroll
        for (int k = 0; k < 8; ++k) {
            int dz = k >> 2, dy = (k >> 1) & 1, dx = k & 1;
            int zc = z0 + dz, yc = y0 + dy, xc = x0 + dx;
            bool valid = ((unsigned)zc < 8u) && ((unsigned)yc < 32u) && ((unsigned)xc < 32u);
            int zcl = min(max(zc, 0), 7), ycl = min(max(yc, 0), 31), xcl = min(max(xc, 0), 31);
            idx8[k] = (zcl * 32 + ycl) * 32 + xcl;
            float wgt = wz[dz] * wy[dy] * wx[dx];
            w8[k] = valid ? wgt : 0.f;
            wsum += w8[k];
        }
        float ax = 0.f, ay = 0.f;
        if (wsum != 0.f) {
#pragma unroll
            for (int k = 0; k < 8; ++k) {
                const float2 v = *(const float2*)(ytn + (size_t)idx8[k] * 128 + 2 * lane);
                ax = fmaf(w8[k], v.x, ax);
                ay = fmaf(w8[k], v.y, ay);
            }
        }
        lds[(2 * lane) * 65 + pt] = ax;
        lds[(2 * lane + 1) * 65 + pt] = ay;
    }
    __syncthreads();
    // coalesced store: 128 channel-rows of 64 points
    const int pw = tid & 63, cw = tid >> 6;
    float* ob = out + (size_t)n * 128 * 65536 + p0 + pw;
#pragma unroll
    for (int k = 0; k < 32; ++k) {
        int c = k * 4 + cw;
        ob[(size_t)c * 65536] = lds[c * 65 + pw];
    }
}

extern "C" void kernel_launch(void* const* d_in, const int* in_sizes, int n_in,
                              void* d_out, int out_size, void* d_ws, size_t ws_size,
                              hipStream_t stream) {
    const float* x     = (const float*)d_in[0];
    const float* y     = (const float*)d_in[1];
    const float* wdh   = (const float*)d_in[2];
    const float* wdl   = (const float*)d_in[3];
    const float* wflow = (const float*)d_in[4];
    const float* watt  = (const float*)d_in[5];
    const float* wconv = (const float*)d_in[6];
    float* out = (float*)d_out;

    float* ws     = (float*)d_ws;
    float* meanx  = ws;                   // 128
    float* wcombT = meanx + 128;          // 8192
    float* hf     = wcombT + 8192;        // 1048576
    float* low2   = hf + 1048576;         // 8388608
    float* hfup   = low2 + 8388608;       // 8388608
    float* vg     = hfup + 8388608;       // 393216

    // partials live in d_out (6.29M floats <= 16.7M); ksample later overwrites all of d_out.
    float* part = out;
    // yt (2.1M floats) reuses the hfup region — hfup is dead after kflowp.
    float* yt = hfup;

    kmean<<<128, 256, 0, stream>>>(x, meanx);
    kprep<<<2, 64, 0, stream>>>(wdl, watt, wconv, meanx, wcombT);
    kconv1l<<<512, 256, 0, stream>>>(x, wcombT, low2);
    kconvh<<<64, 256, 0, stream>>>(y, wdh, hf);
    kups<<<32768, 256, 0, stream>>>(hf, hfup);
    kflowp<<<1024, 256, 0, stream>>>(hfup, low2, wflow, part);
    kcomb<<<512, 256, 0, stream>>>(part, vg);
    ktrans<<<512, 256, 0, stream>>>(y, yt);      // after kflowp: hfup region now free
    ksample<<<2048, 256, 0, stream>>>(yt, vg, out);
}

// Round 7
// 259.531 us; speedup vs baseline: 1.1452x; 1.1452x over previous
//
#include <hip/hip_runtime.h>
#include <math.h>

// x [2,64,16,64,64], y [2,128,8,32,32]
// w_down_h [64,128], w_down_l [64,64], w_flow [3,128,3,3,3],
// w_att_atten [64,64], w_att_conv [64,64]
// out = grid_sample(y, vgrid) -> [2,128,16,64,64] fp32

// ---------------- kernel A: per-channel mean of x ----------------
__global__ void kmean(const float* __restrict__ x, float* __restrict__ meanx) {
    int ch = blockIdx.x;  // 0..127  (n*64+c)
    const float4* base = (const float4*)(x + (size_t)ch * 65536);
    float s = 0.f;
    for (int j = threadIdx.x; j < 16384; j += 256) {
        float4 v = base[j];
        s += v.x + v.y + v.z + v.w;
    }
    __shared__ float red[256];
    red[threadIdx.x] = s;
    __syncthreads();
    for (int off = 128; off > 0; off >>= 1) {
        if (threadIdx.x < off) red[threadIdx.x] += red[threadIdx.x + off];
        __syncthreads();
    }
    if (threadIdx.x == 0) meanx[ch] = red[0] * (1.0f / 65536.0f);
}

// ---------------- kernel B: build W_comb^T per batch ----------------
__global__ void kprep(const float* __restrict__ wdl, const float* __restrict__ watt,
                      const float* __restrict__ wconv, const float* __restrict__ meanx,
                      float* __restrict__ wcombT) {
    int n = blockIdx.x;
    int c = threadIdx.x;  // 64 threads
    __shared__ float pooled[64], sc[64];
    float p = 0.f;
    for (int i = 0; i < 64; ++i) p += wdl[c * 64 + i] * meanx[n * 64 + i];
    pooled[c] = p;
    __syncthreads();
    float a = 0.f;
    for (int i = 0; i < 64; ++i) a += watt[c * 64 + i] * pooled[i];
    sc[c] = 1.f + 1.f / (1.f + expf(-a));
    __syncthreads();
    int o = c;
    for (int i = 0; i < 64; ++i) {
        float acc = 0.f;
        for (int j = 0; j < 64; ++j) acc += wconv[o * 64 + j] * sc[j] * wdl[j * 64 + i];
        wcombT[n * 4096 + i * 64 + o] = acc;
    }
}

// ---------------- kernel C: low2 = W_comb * x ----------------
__global__ __launch_bounds__(256) void kconv1l(const float* __restrict__ x,
                                               const float* __restrict__ wcombT,
                                               float* __restrict__ low2) {
    int b = blockIdx.x;  // 512
    int n = b >> 8, tile = b & 255;
    __shared__ float4 Wl[1024];
    const float4* src = (const float4*)(wcombT + n * 4096);
    for (int k = threadIdx.x; k < 1024; k += 256) Wl[k] = src[k];
    __syncthreads();
    int p = tile * 256 + threadIdx.x;
    float4 acc[16];
#pragma unroll
    for (int o = 0; o < 16; ++o) acc[o] = make_float4(0.f, 0.f, 0.f, 0.f);
    const float* xb = x + (size_t)n * 64 * 65536 + p;
    for (int i = 0; i < 64; ++i) {
        float xi = xb[(size_t)i * 65536];
#pragma unroll
        for (int o = 0; o < 16; ++o) {
            float4 w = Wl[i * 16 + o];
            acc[o].x = fmaf(w.x, xi, acc[o].x);
            acc[o].y = fmaf(w.y, xi, acc[o].y);
            acc[o].z = fmaf(w.z, xi, acc[o].z);
            acc[o].w = fmaf(w.w, xi, acc[o].w);
        }
    }
    float* ob = low2 + (size_t)n * 64 * 65536 + p;
#pragma unroll
    for (int o = 0; o < 16; ++o) {
        ob[(size_t)(4 * o + 0) * 65536] = acc[o].x;
        ob[(size_t)(4 * o + 1) * 65536] = acc[o].y;
        ob[(size_t)(4 * o + 2) * 65536] = acc[o].z;
        ob[(size_t)(4 * o + 3) * 65536] = acc[o].w;
    }
}

// ---------------- kernel D: hf = w_down_h * y ----------------
__global__ __launch_bounds__(256) void kconvh(const float* __restrict__ y,
                                              const float* __restrict__ wdh,
                                              float* __restrict__ hf) {
    int b = blockIdx.x;  // 64
    int n = b >> 5, tile = b & 31;
    __shared__ float Wh[8192];
    for (int k = threadIdx.x; k < 8192; k += 256) {
        int i = k >> 6, o = k & 63;
        Wh[k] = wdh[o * 128 + i];
    }
    __syncthreads();
    int p = tile * 256 + threadIdx.x;
    float4 acc[16];
#pragma unroll
    for (int o = 0; o < 16; ++o) acc[o] = make_float4(0.f, 0.f, 0.f, 0.f);
    const float* yb = y + (size_t)n * 128 * 8192 + p;
    const float4* Wh4 = (const float4*)Wh;
    for (int i = 0; i < 128; ++i) {
        float yi = yb[(size_t)i * 8192];
#pragma unroll
        for (int o = 0; o < 16; ++o) {
            float4 w = Wh4[i * 16 + o];
            acc[o].x = fmaf(w.x, yi, acc[o].x);
            acc[o].y = fmaf(w.y, yi, acc[o].y);
            acc[o].z = fmaf(w.z, yi, acc[o].z);
            acc[o].w = fmaf(w.w, yi, acc[o].w);
        }
    }
    float* ob = hf + (size_t)n * 64 * 8192 + p;
#pragma unroll
    for (int o = 0; o < 16; ++o) {
        ob[(size_t)(4 * o + 0) * 8192] = acc[o].x;
        ob[(size_t)(4 * o + 1) * 8192] = acc[o].y;
        ob[(size_t)(4 * o + 2) * 8192] = acc[o].z;
        ob[(size_t)(4 * o + 3) * 8192] = acc[o].w;
    }
}

// ---------------- kernel E: trilinear upsample (align_corners=True) ----------------
__global__ void kups(const float* __restrict__ hf, float* __restrict__ hfup) {
    int idx = blockIdx.x * 256 + threadIdx.x;  // 8388608 total
    int w = idx & 63, h = (idx >> 6) & 63, d = (idx >> 12) & 15;
    int c = (idx >> 16) & 63, n = idx >> 22;
    const float SD = 7.0f / 15.0f, SH = 31.0f / 63.0f;
    float pd = (float)d * SD, ph = (float)h * SH, pw = (float)w * SH;
    int z0 = (int)pd; if (z0 > 7) z0 = 7;
    int z1 = min(z0 + 1, 7); float fz = pd - (float)z0;
    int y0 = (int)ph; if (y0 > 31) y0 = 31;
    int y1 = min(y0 + 1, 31); float fy = ph - (float)y0;
    int x0 = (int)pw; if (x0 > 31) x0 = 31;
    int x1 = min(x0 + 1, 31); float fx = pw - (float)x0;
    const float* b = hf + (size_t)(n * 64 + c) * 8192;
    float v000 = b[(z0 * 32 + y0) * 32 + x0], v001 = b[(z0 * 32 + y0) * 32 + x1];
    float v010 = b[(z0 * 32 + y1) * 32 + x0], v011 = b[(z0 * 32 + y1) * 32 + x1];
    float v100 = b[(z1 * 32 + y0) * 32 + x0], v101 = b[(z1 * 32 + y0) * 32 + x1];
    float v110 = b[(z1 * 32 + y1) * 32 + x0], v111 = b[(z1 * 32 + y1) * 32 + x1];
    float c00 = v000 + (v001 - v000) * fx;
    float c01 = v010 + (v011 - v010) * fx;
    float c10 = v100 + (v101 - v100) * fx;
    float c11 = v110 + (v111 - v110) * fx;
    float c0 = c00 + (c01 - c00) * fy;
    float c1 = c10 + (c11 - c10) * fy;
    hfup[idx] = c0 + (c1 - c0) * fz;
}

// ---------------- kernel F: 3x3x3 conv partials, LDS tile + register-blocked x8 ----------------
// 32 splits x 4 channels. Block tile 4z x 16y x 32x; thread = (xo:4, ty:16, tz:4),
// 8 consecutive x-outputs x 3 flow channels. LDS [6][18][36] (stride 36 dw = 144B):
// b128 reads conflict-free (8-lane groups hit 8 distinct 4-bank windows), b64 2-way (free).
// part layout: part[((split*2 + n)*3 + o)*65536 + p], 32 splits.
__global__ __launch_bounds__(256) void kflowp(const float* __restrict__ hfup,
                                              const float* __restrict__ low2,
                                              const float* __restrict__ wflow,
                                              float* __restrict__ part) {
    const int b = blockIdx.x;          // 2048
    const int split = b & 31;          // 4 channels each
    const int tile = b >> 5;           // 0..63
    const int n = tile >> 5;
    const int t = tile & 31;           // td(4) th(4) tw(2)
    const int td = t >> 3, th = (t >> 1) & 3, tw = t & 1;
    const int d0 = td * 4, h0 = th * 16, w0 = tw * 32;
    const int tid = threadIdx.x;
    const int xo = tid & 3, ty = (tid >> 2) & 15, tz = tid >> 6;

    __shared__ float lds[3888];  // [z:6][y:18][x:36]

    // one-time staging map: element e = tid + 256k  ->  global offset (or -1)
    int goff[16];
#pragma unroll
    for (int k = 0; k < 16; ++k) {
        const int e = tid + 256 * k;
        const int r = e / 36;            // row 0..107
        const int lx = e - r * 36;
        const int z = r / 18;
        const int ly = r - z * 18;
        const int gz = d0 - 1 + z, gy = h0 - 1 + ly, gx = w0 - 1 + lx;
        const bool ok = (e < 3888) && ((unsigned)gz < 16u) && ((unsigned)gy < 64u) &&
                        ((unsigned)gx < 64u);
        goff[k] = ok ? (gz * 4096 + gy * 64 + gx) : -1;
    }

    float acc[3][8];
#pragma unroll
    for (int o = 0; o < 3; ++o)
#pragma unroll
        for (int j = 0; j < 8; ++j) acc[o][j] = 0.f;

    for (int ci = 0; ci < 4; ++ci) {
        const int cg = split * 4 + ci;
        const float* src = (cg < 64) ? hfup + (size_t)(n * 64 + cg) * 65536
                                     : low2 + (size_t)(n * 64 + cg - 64) * 65536;
        __syncthreads();  // protect prior-iteration reads
#pragma unroll
        for (int k = 0; k < 16; ++k) {
            const int e = tid + 256 * k;
            if (e < 3888) lds[e] = (goff[k] >= 0) ? src[goff[k]] : 0.f;
        }
        __syncthreads();
        const float* wb = wflow + cg * 27;  // block-uniform -> s_loads
#pragma unroll
        for (int dz = 0; dz < 3; ++dz) {
#pragma unroll
            for (int dy = 0; dy < 3; ++dy) {
                const float* rp = &lds[((tz + dz) * 18 + ty + dy) * 36 + 8 * xo];
                const float4 va = *(const float4*)(rp);
                const float4 vb = *(const float4*)(rp + 4);
                const float2 vc = *(const float2*)(rp + 8);
                const float v[10] = {va.x, va.y, va.z, va.w,
                                     vb.x, vb.y, vb.z, vb.w, vc.x, vc.y};
                float wq[3][3];
#pragma unroll
                for (int o = 0; o < 3; ++o)
#pragma unroll
                    for (int dx = 0; dx < 3; ++dx)
                        wq[o][dx] = wb[o * 3456 + (dz * 3 + dy) * 3 + dx];
#pragma unroll
                for (int o = 0; o < 3; ++o)
#pragma unroll
                    for (int j = 0; j < 8; ++j)
#pragma unroll
                        for (int dx = 0; dx < 3; ++dx)
                            acc[o][j] = fmaf(wq[o][dx], v[j + dx], acc[o][j]);
            }
        }
    }

    const int oz = d0 + tz, oy = h0 + ty, ox = w0 + 8 * xo;
    const size_t base = ((size_t)(split * 2 + n)) * 3 * 65536;
    const int p = oz * 4096 + oy * 64 + ox;
#pragma unroll
    for (int o = 0; o < 3; ++o) {
        float* pp = part + base + (size_t)o * 65536 + p;
        *(float4*)(pp)     = make_float4(acc[o][0], acc[o][1], acc[o][2], acc[o][3]);
        *(float4*)(pp + 4) = make_float4(acc[o][4], acc[o][5], acc[o][6], acc[o][7]);
    }
}

// ---------------- kernel F2: combine partials + grid + normalize -> vgrid ----------------
__global__ void kcomb(const float* __restrict__ part, float* __restrict__ vg) {
    int gid = blockIdx.x * 256 + threadIdx.x;  // 131072
    int n = gid >> 16, p = gid & 65535;
    float s0 = 0.f, s1 = 0.f, s2 = 0.f;
    for (int s = 0; s < 32; ++s) {
        const float* bp = part + ((size_t)(s * 2 + n)) * 3 * 65536 + p;
        s0 += bp[0];
        s1 += bp[65536];
        s2 += bp[131072];
    }
    int w = p & 63, h = (p >> 6) & 63, d = p >> 12;
    size_t vb = (size_t)n * 3 * 65536;
    vg[vb + p]          = ((float)w + s0) * (1.0f / 64.0f);
    vg[vb + 65536 + p]  = ((float)h + s1) * (1.0f / 64.0f);
    vg[vb + 131072 + p] = ((float)d + s2) * (1.0f / 16.0f);
}

// ---------------- kernel T: transpose y -> channel-last yt [n][8192][128] ----------------
__global__ __launch_bounds__(256) void ktrans(const float* __restrict__ y,
                                              float* __restrict__ yt) {
    int b = blockIdx.x;       // 512
    int n = b >> 8;
    int rem = b & 255;        // 2 c-tiles * 128 s-tiles
    int ct = rem >> 7, st = rem & 127;
    int c0 = ct * 64, s0 = st * 64;
    __shared__ float t[64][65];
    int tx = threadIdx.x & 63, ty = threadIdx.x >> 6;  // 4 rows/pass
#pragma unroll
    for (int k = 0; k < 16; ++k)
        t[ty + 4 * k][tx] = y[((size_t)(n * 128 + c0 + ty + 4 * k)) * 8192 + s0 + tx];
    __syncthreads();
#pragma unroll
    for (int k = 0; k < 16; ++k)
        yt[((size_t)(n * 8192 + s0 + ty + 4 * k)) * 128 + c0 + tx] = t[tx][ty + 4 * k];
}

// ---------------- kernel G: grid_sample, channel-last gathers ----------------
__global__ __launch_bounds__(256) void ksample(const float* __restrict__ yt,
                                               const float* __restrict__ vg,
                                               float* __restrict__ out) {
    const int b = blockIdx.x;        // 2048
    const int n = b >> 10;
    const int p0 = (b & 1023) << 6;  // 64 points per block
    const int tid = threadIdx.x;
    const int lane = tid & 63;
    const int wv = tid >> 6;         // 0..3

    __shared__ float lds[128 * 65];  // [c][pt], pad 65

    const float* ytn = yt + (size_t)n * 8192 * 128;
    const size_t vb = (size_t)n * 3 * 65536;

    for (int q = 0; q < 16; ++q) {
        const int pt = wv * 16 + q;  // 0..63, wave-uniform
        const int p = p0 + pt;
        float gx = vg[vb + p], gy = vg[vb + 65536 + p], gz = vg[vb + 131072 + p];
        float ix = ((gx + 1.f) * 32.f - 1.f) * 0.5f;
        float iy = ((gy + 1.f) * 32.f - 1.f) * 0.5f;
        float iz = ((gz + 1.f) * 8.f - 1.f) * 0.5f;
        int x0 = (int)floorf(ix), y0 = (int)floorf(iy), z0 = (int)floorf(iz);
        float fx = ix - (float)x0, fy = iy - (float)y0, fz = iz - (float)z0;
        float wx[2] = {1.f - fx, fx}, wy[2] = {1.f - fy, fy}, wz[2] = {1.f - fz, fz};
        int idx8[8];
        float w8[8];
        float wsum = 0.f;
#pragma unroll
        for (int k = 0; k < 8; ++k) {
            int dz = k >> 2, dy = (k >> 1) & 1, dx = k & 1;
            int zc = z0 + dz, yc = y0 + dy, xc = x0 + dx;
            bool valid = ((unsigned)zc < 8u) && ((unsigned)yc < 32u) && ((unsigned)xc < 32u);
            int zcl = min(max(zc, 0), 7), ycl = min(max(yc, 0), 31), xcl = min(max(xc, 0), 31);
            idx8[k] = (zcl * 32 + ycl) * 32 + xcl;
            float wgt = wz[dz] * wy[dy] * wx[dx];
            w8[k] = valid ? wgt : 0.f;
            wsum += w8[k];
        }
        float ax = 0.f, ay = 0.f;
        if (wsum != 0.f) {
#pragma unroll
            for (int k = 0; k < 8; ++k) {
                const float2 v = *(const float2*)(ytn + (size_t)idx8[k] * 128 + 2 * lane);
                ax = fmaf(w8[k], v.x, ax);
                ay = fmaf(w8[k], v.y, ay);
            }
        }
        lds[(2 * lane) * 65 + pt] = ax;
        lds[(2 * lane + 1) * 65 + pt] = ay;
    }
    __syncthreads();
    // coalesced store: 128 channel-rows of 64 points
    const int pw = tid & 63, cw = tid >> 6;
    float* ob = out + (size_t)n * 128 * 65536 + p0 + pw;
#pragma unroll
    for (int k = 0; k < 32; ++k) {
        int c = k * 4 + cw;
        ob[(size_t)c * 65536] = lds[c * 65 + pw];
    }
}

extern "C" void kernel_launch(void* const* d_in, const int* in_sizes, int n_in,
                              void* d_out, int out_size, void* d_ws, size_t ws_size,
                              hipStream_t stream) {
    const float* x     = (const float*)d_in[0];
    const float* y     = (const float*)d_in[1];
    const float* wdh   = (const float*)d_in[2];
    const float* wdl   = (const float*)d_in[3];
    const float* wflow = (const float*)d_in[4];
    const float* watt  = (const float*)d_in[5];
    const float* wconv = (const float*)d_in[6];
    float* out = (float*)d_out;

    float* ws     = (float*)d_ws;
    float* meanx  = ws;                   // 128
    float* wcombT = meanx + 128;          // 8192
    float* hf     = wcombT + 8192;        // 1048576
    float* low2   = hf + 1048576;         // 8388608
    float* hfup   = low2 + 8388608;       // 8388608
    float* vg     = hfup + 8388608;       // 393216

    // partials live in d_out (32*2*3*65536 = 12.58M floats <= 16.77M);
    // fully written by kflowp before kcomb reads; ksample overwrites all of d_out.
    float* part = out;
    // yt (2.1M floats) reuses the hfup region — hfup is dead after kflowp.
    float* yt = hfup;

    kmean<<<128, 256, 0, stream>>>(x, meanx);
    kprep<<<2, 64, 0, stream>>>(wdl, watt, wconv, meanx, wcombT);
    kconv1l<<<512, 256, 0, stream>>>(x, wcombT, low2);
    kconvh<<<64, 256, 0, stream>>>(y, wdh, hf);
    kups<<<32768, 256, 0, stream>>>(hf, hfup);
    kflowp<<<2048, 256, 0, stream>>>(hfup, low2, wflow, part);
    kcomb<<<512, 256, 0, stream>>>(part, vg);
    ktrans<<<512, 256, 0, stream>>>(y, yt);      // after kflowp: hfup region now free
    ksample<<<2048, 256, 0, stream>>>(yt, vg, out);
}

// Round 8
// 254.218 us; speedup vs baseline: 1.1691x; 1.0209x over previous
//
#include <hip/hip_runtime.h>
#include <math.h>

// x [2,64,16,64,64], y [2,128,8,32,32]
// w_down_h [64,128], w_down_l [64,64], w_flow [3,128,3,3,3],
// w_att_atten [64,64], w_att_conv [64,64]
// out = grid_sample(y, vgrid) -> [2,128,16,64,64] fp32

// ---------------- kernel A: per-channel mean of x ----------------
__global__ void kmean(const float* __restrict__ x, float* __restrict__ meanx) {
    int ch = blockIdx.x;  // 0..127  (n*64+c)
    const float4* base = (const float4*)(x + (size_t)ch * 65536);
    float s = 0.f;
    for (int j = threadIdx.x; j < 16384; j += 256) {
        float4 v = base[j];
        s += v.x + v.y + v.z + v.w;
    }
    __shared__ float red[256];
    red[threadIdx.x] = s;
    __syncthreads();
    for (int off = 128; off > 0; off >>= 1) {
        if (threadIdx.x < off) red[threadIdx.x] += red[threadIdx.x + off];
        __syncthreads();
    }
    if (threadIdx.x == 0) meanx[ch] = red[0] * (1.0f / 65536.0f);
}

// ---------------- kernel B: build W_comb^T per batch ----------------
__global__ void kprep(const float* __restrict__ wdl, const float* __restrict__ watt,
                      const float* __restrict__ wconv, const float* __restrict__ meanx,
                      float* __restrict__ wcombT) {
    int n = blockIdx.x;
    int c = threadIdx.x;  // 64 threads
    __shared__ float pooled[64], sc[64];
    float p = 0.f;
    for (int i = 0; i < 64; ++i) p += wdl[c * 64 + i] * meanx[n * 64 + i];
    pooled[c] = p;
    __syncthreads();
    float a = 0.f;
    for (int i = 0; i < 64; ++i) a += watt[c * 64 + i] * pooled[i];
    sc[c] = 1.f + 1.f / (1.f + expf(-a));
    __syncthreads();
    int o = c;
    for (int i = 0; i < 64; ++i) {
        float acc = 0.f;
        for (int j = 0; j < 64; ++j) acc += wconv[o * 64 + j] * sc[j] * wdl[j * 64 + i];
        wcombT[n * 4096 + i * 64 + o] = acc;
    }
}

// ---------------- kernel C: low2 = W_comb * x ----------------
__global__ __launch_bounds__(256) void kconv1l(const float* __restrict__ x,
                                               const float* __restrict__ wcombT,
                                               float* __restrict__ low2) {
    int b = blockIdx.x;  // 512
    int n = b >> 8, tile = b & 255;
    __shared__ float4 Wl[1024];
    const float4* src = (const float4*)(wcombT + n * 4096);
    for (int k = threadIdx.x; k < 1024; k += 256) Wl[k] = src[k];
    __syncthreads();
    int p = tile * 256 + threadIdx.x;
    float4 acc[16];
#pragma unroll
    for (int o = 0; o < 16; ++o) acc[o] = make_float4(0.f, 0.f, 0.f, 0.f);
    const float* xb = x + (size_t)n * 64 * 65536 + p;
    for (int i = 0; i < 64; ++i) {
        float xi = xb[(size_t)i * 65536];
#pragma unroll
        for (int o = 0; o < 16; ++o) {
            float4 w = Wl[i * 16 + o];
            acc[o].x = fmaf(w.x, xi, acc[o].x);
            acc[o].y = fmaf(w.y, xi, acc[o].y);
            acc[o].z = fmaf(w.z, xi, acc[o].z);
            acc[o].w = fmaf(w.w, xi, acc[o].w);
        }
    }
    float* ob = low2 + (size_t)n * 64 * 65536 + p;
#pragma unroll
    for (int o = 0; o < 16; ++o) {
        ob[(size_t)(4 * o + 0) * 65536] = acc[o].x;
        ob[(size_t)(4 * o + 1) * 65536] = acc[o].y;
        ob[(size_t)(4 * o + 2) * 65536] = acc[o].z;
        ob[(size_t)(4 * o + 3) * 65536] = acc[o].w;
    }
}

// ---------------- kernel D: hf = w_down_h * y ----------------
__global__ __launch_bounds__(256) void kconvh(const float* __restrict__ y,
                                              const float* __restrict__ wdh,
                                              float* __restrict__ hf) {
    int b = blockIdx.x;  // 64
    int n = b >> 5, tile = b & 31;
    __shared__ float Wh[8192];
    for (int k = threadIdx.x; k < 8192; k += 256) {
        int i = k >> 6, o = k & 63;
        Wh[k] = wdh[o * 128 + i];
    }
    __syncthreads();
    int p = tile * 256 + threadIdx.x;
    float4 acc[16];
#pragma unroll
    for (int o = 0; o < 16; ++o) acc[o] = make_float4(0.f, 0.f, 0.f, 0.f);
    const float* yb = y + (size_t)n * 128 * 8192 + p;
    const float4* Wh4 = (const float4*)Wh;
    for (int i = 0; i < 128; ++i) {
        float yi = yb[(size_t)i * 8192];
#pragma unroll
        for (int o = 0; o < 16; ++o) {
            float4 w = Wh4[i * 16 + o];
            acc[o].x = fmaf(w.x, yi, acc[o].x);
            acc[o].y = fmaf(w.y, yi, acc[o].y);
            acc[o].z = fmaf(w.z, yi, acc[o].z);
            acc[o].w = fmaf(w.w, yi, acc[o].w);
        }
    }
    float* ob = hf + (size_t)n * 64 * 8192 + p;
#pragma unroll
    for (int o = 0; o < 16; ++o) {
        ob[(size_t)(4 * o + 0) * 8192] = acc[o].x;
        ob[(size_t)(4 * o + 1) * 8192] = acc[o].y;
        ob[(size_t)(4 * o + 2) * 8192] = acc[o].z;
        ob[(size_t)(4 * o + 3) * 8192] = acc[o].w;
    }
}

// ---------------- kernel E: trilinear upsample (align_corners=True) ----------------
__global__ void kups(const float* __restrict__ hf, float* __restrict__ hfup) {
    int idx = blockIdx.x * 256 + threadIdx.x;  // 8388608 total
    int w = idx & 63, h = (idx >> 6) & 63, d = (idx >> 12) & 15;
    int c = (idx >> 16) & 63, n = idx >> 22;
    const float SD = 7.0f / 15.0f, SH = 31.0f / 63.0f;
    float pd = (float)d * SD, ph = (float)h * SH, pw = (float)w * SH;
    int z0 = (int)pd; if (z0 > 7) z0 = 7;
    int z1 = min(z0 + 1, 7); float fz = pd - (float)z0;
    int y0 = (int)ph; if (y0 > 31) y0 = 31;
    int y1 = min(y0 + 1, 31); float fy = ph - (float)y0;
    int x0 = (int)pw; if (x0 > 31) x0 = 31;
    int x1 = min(x0 + 1, 31); float fx = pw - (float)x0;
    const float* b = hf + (size_t)(n * 64 + c) * 8192;
    float v000 = b[(z0 * 32 + y0) * 32 + x0], v001 = b[(z0 * 32 + y0) * 32 + x1];
    float v010 = b[(z0 * 32 + y1) * 32 + x0], v011 = b[(z0 * 32 + y1) * 32 + x1];
    float v100 = b[(z1 * 32 + y0) * 32 + x0], v101 = b[(z1 * 32 + y0) * 32 + x1];
    float v110 = b[(z1 * 32 + y1) * 32 + x0], v111 = b[(z1 * 32 + y1) * 32 + x1];
    float c00 = v000 + (v001 - v000) * fx;
    float c01 = v010 + (v011 - v010) * fx;
    float c10 = v100 + (v101 - v100) * fx;
    float c11 = v110 + (v111 - v110) * fx;
    float c0 = c00 + (c01 - c00) * fy;
    float c1 = c10 + (c11 - c10) * fy;
    hfup[idx] = c0 + (c1 - c0) * fz;
}

// ---------------- kernel F: 3x3x3 conv partials, dbuf LDS + split staging ----------------
// 16 splits x 8 channels. Block tile 4z x 16y x 32x; thread = (xo:4, ty:16, tz:4),
// 8 consecutive x-outputs x 3 flow channels. LDS [2][6][18][36], double-buffered:
// next channel's global loads issue BEFORE compute (latency hides under 648 FMA),
// ds_write after, one barrier per channel.
// part layout: part[((split*2 + n)*3 + o)*65536 + p], 16 splits.
__global__ __launch_bounds__(256) void kflowp(const float* __restrict__ hfup,
                                              const float* __restrict__ low2,
                                              const float* __restrict__ wflow,
                                              float* __restrict__ part) {
    const int b = blockIdx.x;          // 1024
    const int split = b & 15;          // 8 channels each
    const int tile = b >> 4;           // 0..63
    const int n = tile >> 5;
    const int t = tile & 31;           // td(4) th(4) tw(2)
    const int td = t >> 3, th = (t >> 1) & 3, tw = t & 1;
    const int d0 = td * 4, h0 = th * 16, w0 = tw * 32;
    const int tid = threadIdx.x;
    const int xo = tid & 3, ty = (tid >> 2) & 15, tz = tid >> 6;

    __shared__ float lds[2][3888];  // [z:6][y:18][x:36] each

    // one-time staging map: element e = tid + 256k -> global offset (or -1)
    int goff[16];
#pragma unroll
    for (int k = 0; k < 16; ++k) {
        const int e = tid + 256 * k;
        const int r = e / 36;            // row 0..107
        const int lx = e - r * 36;
        const int z = r / 18;
        const int ly = r - z * 18;
        const int gz = d0 - 1 + z, gy = h0 - 1 + ly, gx = w0 - 1 + lx;
        const bool ok = (e < 3888) && ((unsigned)gz < 16u) && ((unsigned)gy < 64u) &&
                        ((unsigned)gx < 64u);
        goff[k] = ok ? (gz * 4096 + gy * 64 + gx) : -1;
    }

    // channels 8*split..8*split+7 all come from one source tensor
    const float* srcb = (split < 8)
        ? hfup + (size_t)(n * 64 + split * 8) * 65536
        : low2 + (size_t)(n * 64 + (split - 8) * 8) * 65536;

    float acc[3][8];
#pragma unroll
    for (int o = 0; o < 3; ++o)
#pragma unroll
        for (int j = 0; j < 8; ++j) acc[o][j] = 0.f;

    // stage channel 0 into buffer 0
#pragma unroll
    for (int k = 0; k < 16; ++k) {
        const int e = tid + 256 * k;
        if (e < 3888) lds[0][e] = (goff[k] >= 0) ? srcb[goff[k]] : 0.f;
    }
    __syncthreads();

    const int wch0 = (split < 8) ? split * 8 : split * 8;  // global channel base
    for (int ci = 0; ci < 8; ++ci) {
        // T14 split-stage: issue next channel's loads first
        float stg[16];
        if (ci < 7) {
            const float* src = srcb + (size_t)(ci + 1) * 65536;
#pragma unroll
            for (int k = 0; k < 16; ++k)
                stg[k] = (goff[k] >= 0) ? src[goff[k]] : 0.f;
        }
        // compute from current buffer (648 FMA) — hides the loads above
        const float* wb = wflow + (size_t)(split * 8 + ci) * 27;  // block-uniform
        const float* buf = lds[ci & 1];
#pragma unroll
        for (int dz = 0; dz < 3; ++dz) {
#pragma unroll
            for (int dy = 0; dy < 3; ++dy) {
                const float* rp = &buf[((tz + dz) * 18 + ty + dy) * 36 + 8 * xo];
                const float4 va = *(const float4*)(rp);
                const float4 vb = *(const float4*)(rp + 4);
                const float2 vc = *(const float2*)(rp + 8);
                const float v[10] = {va.x, va.y, va.z, va.w,
                                     vb.x, vb.y, vb.z, vb.w, vc.x, vc.y};
                float wq[3][3];
#pragma unroll
                for (int o = 0; o < 3; ++o)
#pragma unroll
                    for (int dx = 0; dx < 3; ++dx)
                        wq[o][dx] = wb[o * 3456 + (dz * 3 + dy) * 3 + dx];
#pragma unroll
                for (int o = 0; o < 3; ++o)
#pragma unroll
                    for (int j = 0; j < 8; ++j)
#pragma unroll
                        for (int dx = 0; dx < 3; ++dx)
                            acc[o][j] = fmaf(wq[o][dx], v[j + dx], acc[o][j]);
            }
        }
        // write staged data to the other buffer, then barrier
        if (ci < 7) {
            float* dst = lds[(ci + 1) & 1];
#pragma unroll
            for (int k = 0; k < 16; ++k) {
                const int e = tid + 256 * k;
                if (e < 3888) dst[e] = stg[k];
            }
            __syncthreads();
        }
    }

    const int oz = d0 + tz, oy = h0 + ty, ox = w0 + 8 * xo;
    const size_t base = ((size_t)(split * 2 + n)) * 3 * 65536;
    const int p = oz * 4096 + oy * 64 + ox;
#pragma unroll
    for (int o = 0; o < 3; ++o) {
        float* pp = part + base + (size_t)o * 65536 + p;
        *(float4*)(pp)     = make_float4(acc[o][0], acc[o][1], acc[o][2], acc[o][3]);
        *(float4*)(pp + 4) = make_float4(acc[o][4], acc[o][5], acc[o][6], acc[o][7]);
    }
}

// ---------------- kernel F2: combine partials + grid + normalize -> vgrid ----------------
__global__ void kcomb(const float* __restrict__ part, float* __restrict__ vg) {
    int gid = blockIdx.x * 256 + threadIdx.x;  // 131072
    int n = gid >> 16, p = gid & 65535;
    float s0 = 0.f, s1 = 0.f, s2 = 0.f;
    for (int s = 0; s < 16; ++s) {
        const float* bp = part + ((size_t)(s * 2 + n)) * 3 * 65536 + p;
        s0 += bp[0];
        s1 += bp[65536];
        s2 += bp[131072];
    }
    int w = p & 63, h = (p >> 6) & 63, d = p >> 12;
    size_t vb = (size_t)n * 3 * 65536;
    vg[vb + p]          = ((float)w + s0) * (1.0f / 64.0f);
    vg[vb + 65536 + p]  = ((float)h + s1) * (1.0f / 64.0f);
    vg[vb + 131072 + p] = ((float)d + s2) * (1.0f / 16.0f);
}

// ---------------- kernel T: transpose y -> channel-last yt [n][8192][128] ----------------
__global__ __launch_bounds__(256) void ktrans(const float* __restrict__ y,
                                              float* __restrict__ yt) {
    int b = blockIdx.x;       // 512
    int n = b >> 8;
    int rem = b & 255;        // 2 c-tiles * 128 s-tiles
    int ct = rem >> 7, st = rem & 127;
    int c0 = ct * 64, s0 = st * 64;
    __shared__ float t[64][65];
    int tx = threadIdx.x & 63, ty = threadIdx.x >> 6;  // 4 rows/pass
#pragma unroll
    for (int k = 0; k < 16; ++k)
        t[ty + 4 * k][tx] = y[((size_t)(n * 128 + c0 + ty + 4 * k)) * 8192 + s0 + tx];
    __syncthreads();
#pragma unroll
    for (int k = 0; k < 16; ++k)
        yt[((size_t)(n * 8192 + s0 + ty + 4 * k)) * 128 + c0 + tx] = t[tx][ty + 4 * k];
}

// ---------------- kernel G: grid_sample, channel-last gathers ----------------
__global__ __launch_bounds__(256) void ksample(const float* __restrict__ yt,
                                               const float* __restrict__ vg,
                                               float* __restrict__ out) {
    const int b = blockIdx.x;        // 2048
    const int n = b >> 10;
    const int p0 = (b & 1023) << 6;  // 64 points per block
    const int tid = threadIdx.x;
    const int lane = tid & 63;
    const int wv = tid >> 6;         // 0..3

    __shared__ float lds[128 * 65];  // [c][pt], pad 65

    const float* ytn = yt + (size_t)n * 8192 * 128;
    const size_t vb = (size_t)n * 3 * 65536;

    for (int q = 0; q < 16; ++q) {
        const int pt = wv * 16 + q;  // 0..63, wave-uniform
        const int p = p0 + pt;
        float gx = vg[vb + p], gy = vg[vb + 65536 + p], gz = vg[vb + 131072 + p];
        float ix = ((gx + 1.f) * 32.f - 1.f) * 0.5f;
        float iy = ((gy + 1.f) * 32.f - 1.f) * 0.5f;
        float iz = ((gz + 1.f) * 8.f - 1.f) * 0.5f;
        int x0 = (int)floorf(ix), y0 = (int)floorf(iy), z0 = (int)floorf(iz);
        float fx = ix - (float)x0, fy = iy - (float)y0, fz = iz - (float)z0;
        float wx[2] = {1.f - fx, fx}, wy[2] = {1.f - fy, fy}, wz[2] = {1.f - fz, fz};
        int idx8[8];
        float w8[8];
        float wsum = 0.f;
#pragma unroll
        for (int k = 0; k < 8; ++k) {
            int dz = k >> 2, dy = (k >> 1) & 1, dx = k & 1;
            int zc = z0 + dz, yc = y0 + dy, xc = x0 + dx;
            bool valid = ((unsigned)zc < 8u) && ((unsigned)yc < 32u) && ((unsigned)xc < 32u);
            int zcl = min(max(zc, 0), 7), ycl = min(max(yc, 0), 31), xcl = min(max(xc, 0), 31);
            idx8[k] = (zcl * 32 + ycl) * 32 + xcl;
            float wgt = wz[dz] * wy[dy] * wx[dx];
            w8[k] = valid ? wgt : 0.f;
            wsum += w8[k];
        }
        float ax = 0.f, ay = 0.f;
        if (wsum != 0.f) {
#pragma unroll
            for (int k = 0; k < 8; ++k) {
                const float2 v = *(const float2*)(ytn + (size_t)idx8[k] * 128 + 2 * lane);
                ax = fmaf(w8[k], v.x, ax);
                ay = fmaf(w8[k], v.y, ay);
            }
        }
        lds[(2 * lane) * 65 + pt] = ax;
        lds[(2 * lane + 1) * 65 + pt] = ay;
    }
    __syncthreads();
    // coalesced store: 128 channel-rows of 64 points
    const int pw = tid & 63, cw = tid >> 6;
    float* ob = out + (size_t)n * 128 * 65536 + p0 + pw;
#pragma unroll
    for (int k = 0; k < 32; ++k) {
        int c = k * 4 + cw;
        ob[(size_t)c * 65536] = lds[c * 65 + pw];
    }
}

extern "C" void kernel_launch(void* const* d_in, const int* in_sizes, int n_in,
                              void* d_out, int out_size, void* d_ws, size_t ws_size,
                              hipStream_t stream) {
    const float* x     = (const float*)d_in[0];
    const float* y     = (const float*)d_in[1];
    const float* wdh   = (const float*)d_in[2];
    const float* wdl   = (const float*)d_in[3];
    const float* wflow = (const float*)d_in[4];
    const float* watt  = (const float*)d_in[5];
    const float* wconv = (const float*)d_in[6];
    float* out = (float*)d_out;

    float* ws     = (float*)d_ws;
    float* meanx  = ws;                   // 128
    float* wcombT = meanx + 128;          // 8192
    float* hf     = wcombT + 8192;        // 1048576
    float* low2   = hf + 1048576;         // 8388608
    float* hfup   = low2 + 8388608;       // 8388608
    float* vg     = hfup + 8388608;       // 393216

    // partials live in d_out (16*2*3*65536 = 6.29M floats <= 16.77M);
    // fully written by kflowp before kcomb reads; ksample overwrites all of d_out.
    float* part = out;
    // yt (2.1M floats) reuses the hfup region — hfup is dead after kflowp.
    float* yt = hfup;

    kmean<<<128, 256, 0, stream>>>(x, meanx);
    kprep<<<2, 64, 0, stream>>>(wdl, watt, wconv, meanx, wcombT);
    kconv1l<<<512, 256, 0, stream>>>(x, wcombT, low2);
    kconvh<<<64, 256, 0, stream>>>(y, wdh, hf);
    kups<<<32768, 256, 0, stream>>>(hf, hfup);
    kflowp<<<1024, 256, 0, stream>>>(hfup, low2, wflow, part);
    kcomb<<<512, 256, 0, stream>>>(part, vg);
    ktrans<<<512, 256, 0, stream>>>(y, yt);      // after kflowp: hfup region now free
    ksample<<<2048, 256, 0, stream>>>(yt, vg, out);
}

// Round 9
// 239.150 us; speedup vs baseline: 1.2428x; 1.0630x over previous
//
#include <hip/hip_runtime.h>
#include <math.h>

// x [2,64,16,64,64], y [2,128,8,32,32]
// w_down_h [64,128], w_down_l [64,64], w_flow [3,128,3,3,3],
// w_att_atten [64,64], w_att_conv [64,64]
// out = grid_sample(y, vgrid) -> [2,128,16,64,64] fp32

// ---------------- kernel A: per-channel mean of x ----------------
__global__ void kmean(const float* __restrict__ x, float* __restrict__ meanx) {
    int ch = blockIdx.x;  // 0..127  (n*64+c)
    const float4* base = (const float4*)(x + (size_t)ch * 65536);
    float s = 0.f;
    for (int j = threadIdx.x; j < 16384; j += 256) {
        float4 v = base[j];
        s += v.x + v.y + v.z + v.w;
    }
    __shared__ float red[256];
    red[threadIdx.x] = s;
    __syncthreads();
    for (int off = 128; off > 0; off >>= 1) {
        if (threadIdx.x < off) red[threadIdx.x] += red[threadIdx.x + off];
        __syncthreads();
    }
    if (threadIdx.x == 0) meanx[ch] = red[0] * (1.0f / 65536.0f);
}

// ---------------- kernel B: build W_comb^T per batch ----------------
__global__ void kprep(const float* __restrict__ wdl, const float* __restrict__ watt,
                      const float* __restrict__ wconv, const float* __restrict__ meanx,
                      float* __restrict__ wcombT) {
    int n = blockIdx.x;
    int c = threadIdx.x;  // 64 threads
    __shared__ float pooled[64], sc[64];
    float p = 0.f;
    for (int i = 0; i < 64; ++i) p += wdl[c * 64 + i] * meanx[n * 64 + i];
    pooled[c] = p;
    __syncthreads();
    float a = 0.f;
    for (int i = 0; i < 64; ++i) a += watt[c * 64 + i] * pooled[i];
    sc[c] = 1.f + 1.f / (1.f + expf(-a));
    __syncthreads();
    int o = c;
    for (int i = 0; i < 64; ++i) {
        float acc = 0.f;
        for (int j = 0; j < 64; ++j) acc += wconv[o * 64 + j] * sc[j] * wdl[j * 64 + i];
        wcombT[n * 4096 + i * 64 + o] = acc;
    }
}

// ---------------- kernel C: low2 = W_comb * x  (4 inputs in flight) ----------------
__global__ __launch_bounds__(256) void kconv1l(const float* __restrict__ x,
                                               const float* __restrict__ wcombT,
                                               float* __restrict__ low2) {
    int b = blockIdx.x;  // 512
    int n = b >> 8, tile = b & 255;
    __shared__ float4 Wl[1024];
    const float4* src = (const float4*)(wcombT + n * 4096);
    for (int k = threadIdx.x; k < 1024; k += 256) Wl[k] = src[k];
    __syncthreads();
    int p = tile * 256 + threadIdx.x;
    float4 acc[16];
#pragma unroll
    for (int o = 0; o < 16; ++o) acc[o] = make_float4(0.f, 0.f, 0.f, 0.f);
    const float* xb = x + (size_t)n * 64 * 65536 + p;
    for (int i = 0; i < 64; i += 4) {
        float xi0 = xb[(size_t)(i + 0) * 65536];
        float xi1 = xb[(size_t)(i + 1) * 65536];
        float xi2 = xb[(size_t)(i + 2) * 65536];
        float xi3 = xb[(size_t)(i + 3) * 65536];
#pragma unroll
        for (int o = 0; o < 16; ++o) {
            float4 w0 = Wl[(i + 0) * 16 + o];
            float4 w1 = Wl[(i + 1) * 16 + o];
            float4 w2 = Wl[(i + 2) * 16 + o];
            float4 w3 = Wl[(i + 3) * 16 + o];
            float ax = acc[o].x, ay = acc[o].y, az = acc[o].z, aw = acc[o].w;
            ax = fmaf(w0.x, xi0, ax); ay = fmaf(w0.y, xi0, ay);
            az = fmaf(w0.z, xi0, az); aw = fmaf(w0.w, xi0, aw);
            ax = fmaf(w1.x, xi1, ax); ay = fmaf(w1.y, xi1, ay);
            az = fmaf(w1.z, xi1, az); aw = fmaf(w1.w, xi1, aw);
            ax = fmaf(w2.x, xi2, ax); ay = fmaf(w2.y, xi2, ay);
            az = fmaf(w2.z, xi2, az); aw = fmaf(w2.w, xi2, aw);
            ax = fmaf(w3.x, xi3, ax); ay = fmaf(w3.y, xi3, ay);
            az = fmaf(w3.z, xi3, az); aw = fmaf(w3.w, xi3, aw);
            acc[o] = make_float4(ax, ay, az, aw);
        }
    }
    float* ob = low2 + (size_t)n * 64 * 65536 + p;
#pragma unroll
    for (int o = 0; o < 16; ++o) {
        ob[(size_t)(4 * o + 0) * 65536] = acc[o].x;
        ob[(size_t)(4 * o + 1) * 65536] = acc[o].y;
        ob[(size_t)(4 * o + 2) * 65536] = acc[o].z;
        ob[(size_t)(4 * o + 3) * 65536] = acc[o].w;
    }
}

// ---------------- kernel D: hf = w_down_h * y  (4 inputs in flight) ----------------
__global__ __launch_bounds__(256) void kconvh(const float* __restrict__ y,
                                              const float* __restrict__ wdh,
                                              float* __restrict__ hf) {
    int b = blockIdx.x;  // 64
    int n = b >> 5, tile = b & 31;
    __shared__ float Wh[8192];
    for (int k = threadIdx.x; k < 8192; k += 256) {
        int i = k >> 6, o = k & 63;
        Wh[k] = wdh[o * 128 + i];
    }
    __syncthreads();
    int p = tile * 256 + threadIdx.x;
    float4 acc[16];
#pragma unroll
    for (int o = 0; o < 16; ++o) acc[o] = make_float4(0.f, 0.f, 0.f, 0.f);
    const float* yb = y + (size_t)n * 128 * 8192 + p;
    const float4* Wh4 = (const float4*)Wh;
    for (int i = 0; i < 128; i += 4) {
        float yi0 = yb[(size_t)(i + 0) * 8192];
        float yi1 = yb[(size_t)(i + 1) * 8192];
        float yi2 = yb[(size_t)(i + 2) * 8192];
        float yi3 = yb[(size_t)(i + 3) * 8192];
#pragma unroll
        for (int o = 0; o < 16; ++o) {
            float4 w0 = Wh4[(i + 0) * 16 + o];
            float4 w1 = Wh4[(i + 1) * 16 + o];
            float4 w2 = Wh4[(i + 2) * 16 + o];
            float4 w3 = Wh4[(i + 3) * 16 + o];
            float ax = acc[o].x, ay = acc[o].y, az = acc[o].z, aw = acc[o].w;
            ax = fmaf(w0.x, yi0, ax); ay = fmaf(w0.y, yi0, ay);
            az = fmaf(w0.z, yi0, az); aw = fmaf(w0.w, yi0, aw);
            ax = fmaf(w1.x, yi1, ax); ay = fmaf(w1.y, yi1, ay);
            az = fmaf(w1.z, yi1, az); aw = fmaf(w1.w, yi1, aw);
            ax = fmaf(w2.x, yi2, ax); ay = fmaf(w2.y, yi2, ay);
            az = fmaf(w2.z, yi2, az); aw = fmaf(w2.w, yi2, aw);
            ax = fmaf(w3.x, yi3, ax); ay = fmaf(w3.y, yi3, ay);
            az = fmaf(w3.z, yi3, az); aw = fmaf(w3.w, yi3, aw);
            acc[o] = make_float4(ax, ay, az, aw);
        }
    }
    float* ob = hf + (size_t)n * 64 * 8192 + p;
#pragma unroll
    for (int o = 0; o < 16; ++o) {
        ob[(size_t)(4 * o + 0) * 8192] = acc[o].x;
        ob[(size_t)(4 * o + 1) * 8192] = acc[o].y;
        ob[(size_t)(4 * o + 2) * 8192] = acc[o].z;
        ob[(size_t)(4 * o + 3) * 8192] = acc[o].w;
    }
}

// ---------------- kernel E: trilinear upsample (align_corners=True) ----------------
__global__ void kups(const float* __restrict__ hf, float* __restrict__ hfup) {
    int idx = blockIdx.x * 256 + threadIdx.x;  // 8388608 total
    int w = idx & 63, h = (idx >> 6) & 63, d = (idx >> 12) & 15;
    int c = (idx >> 16) & 63, n = idx >> 22;
    const float SD = 7.0f / 15.0f, SH = 31.0f / 63.0f;
    float pd = (float)d * SD, ph = (float)h * SH, pw = (float)w * SH;
    int z0 = (int)pd; if (z0 > 7) z0 = 7;
    int z1 = min(z0 + 1, 7); float fz = pd - (float)z0;
    int y0 = (int)ph; if (y0 > 31) y0 = 31;
    int y1 = min(y0 + 1, 31); float fy = ph - (float)y0;
    int x0 = (int)pw; if (x0 > 31) x0 = 31;
    int x1 = min(x0 + 1, 31); float fx = pw - (float)x0;
    const float* b = hf + (size_t)(n * 64 + c) * 8192;
    float v000 = b[(z0 * 32 + y0) * 32 + x0], v001 = b[(z0 * 32 + y0) * 32 + x1];
    float v010 = b[(z0 * 32 + y1) * 32 + x0], v011 = b[(z0 * 32 + y1) * 32 + x1];
    float v100 = b[(z1 * 32 + y0) * 32 + x0], v101 = b[(z1 * 32 + y0) * 32 + x1];
    float v110 = b[(z1 * 32 + y1) * 32 + x0], v111 = b[(z1 * 32 + y1) * 32 + x1];
    float c00 = v000 + (v001 - v000) * fx;
    float c01 = v010 + (v011 - v010) * fx;
    float c10 = v100 + (v101 - v100) * fx;
    float c11 = v110 + (v111 - v110) * fx;
    float c0 = c00 + (c01 - c00) * fy;
    float c1 = c10 + (c11 - c10) * fy;
    hfup[idx] = c0 + (c1 - c0) * fz;
}

// ---------------- kernel F: 3x3x3 conv partials, conflict-free LDS (stride 34, b64) ----------------
// 16 splits x 8 channels, dbuf LDS, reg split-staging. Row stride 34 dwords:
// b64 start bank = (2*ty + 8*xo) mod 32 -> 16 even residues, 4 lanes each ->
// every ds_read_b64 is exactly 4 accesses/bank = its minimum -> conflict-free.
__global__ __launch_bounds__(256) void kflowp(const float* __restrict__ hfup,
                                              const float* __restrict__ low2,
                                              const float* __restrict__ wflow,
                                              float* __restrict__ part) {
    const int b = blockIdx.x;          // 1024
    const int split = b & 15;          // 8 channels each
    const int tile = b >> 4;           // 0..63
    const int n = tile >> 5;
    const int t = tile & 31;           // td(4) th(4) tw(2)
    const int td = t >> 3, th = (t >> 1) & 3, tw = t & 1;
    const int d0 = td * 4, h0 = th * 16, w0 = tw * 32;
    const int tid = threadIdx.x;
    const int xo = tid & 3, ty = (tid >> 2) & 15, tz = tid >> 6;

    __shared__ float lds[2][3672];  // [z:6][y:18][x:34 dw rows]

    // one-time staging map: element e = tid + 256k -> global offset (or -1)
    int goff[15];
#pragma unroll
    for (int k = 0; k < 15; ++k) {
        const int e = tid + 256 * k;
        const int r = e / 34;            // row 0..107
        const int lx = e - r * 34;
        const int z = r / 18;
        const int ly = r - z * 18;
        const int gz = d0 - 1 + z, gy = h0 - 1 + ly, gx = w0 - 1 + lx;
        const bool ok = (e < 3672) && ((unsigned)gz < 16u) && ((unsigned)gy < 64u) &&
                        ((unsigned)gx < 64u);
        goff[k] = ok ? (gz * 4096 + gy * 64 + gx) : -1;
    }

    const float* srcb = (split < 8)
        ? hfup + (size_t)(n * 64 + split * 8) * 65536
        : low2 + (size_t)(n * 64 + (split - 8) * 8) * 65536;

    float acc[3][8];
#pragma unroll
    for (int o = 0; o < 3; ++o)
#pragma unroll
        for (int j = 0; j < 8; ++j) acc[o][j] = 0.f;

    // stage channel 0 into buffer 0
#pragma unroll
    for (int k = 0; k < 15; ++k) {
        const int e = tid + 256 * k;
        if (e < 3672) lds[0][e] = (goff[k] >= 0) ? srcb[goff[k]] : 0.f;
    }
    __syncthreads();

    for (int ci = 0; ci < 8; ++ci) {
        // split-stage: issue next channel's loads first (hide under FMA)
        float stg[15];
        if (ci < 7) {
            const float* src = srcb + (size_t)(ci + 1) * 65536;
#pragma unroll
            for (int k = 0; k < 15; ++k)
                stg[k] = (goff[k] >= 0) ? src[goff[k]] : 0.f;
        }
        const float* wb = wflow + (size_t)(split * 8 + ci) * 27;  // block-uniform
        const float* buf = lds[ci & 1];
#pragma unroll
        for (int dz = 0; dz < 3; ++dz) {
#pragma unroll
            for (int dy = 0; dy < 3; ++dy) {
                const float* rp = &buf[((tz + dz) * 18 + ty + dy) * 34 + 8 * xo];
                const float2 a0 = *(const float2*)(rp);
                const float2 a1 = *(const float2*)(rp + 2);
                const float2 a2 = *(const float2*)(rp + 4);
                const float2 a3 = *(const float2*)(rp + 6);
                const float2 a4 = *(const float2*)(rp + 8);
                const float v[10] = {a0.x, a0.y, a1.x, a1.y, a2.x,
                                     a2.y, a3.x, a3.y, a4.x, a4.y};
                float wq[3][3];
#pragma unroll
                for (int o = 0; o < 3; ++o)
#pragma unroll
                    for (int dx = 0; dx < 3; ++dx)
                        wq[o][dx] = wb[o * 3456 + (dz * 3 + dy) * 3 + dx];
#pragma unroll
                for (int o = 0; o < 3; ++o)
#pragma unroll
                    for (int j = 0; j < 8; ++j)
#pragma unroll
                        for (int dx = 0; dx < 3; ++dx)
                            acc[o][j] = fmaf(wq[o][dx], v[j + dx], acc[o][j]);
            }
        }
        if (ci < 7) {
            float* dst = lds[(ci + 1) & 1];
#pragma unroll
            for (int k = 0; k < 15; ++k) {
                const int e = tid + 256 * k;
                if (e < 3672) dst[e] = stg[k];
            }
            __syncthreads();
        }
    }

    const int oz = d0 + tz, oy = h0 + ty, ox = w0 + 8 * xo;
    const size_t base = ((size_t)(split * 2 + n)) * 3 * 65536;
    const int p = oz * 4096 + oy * 64 + ox;
#pragma unroll
    for (int o = 0; o < 3; ++o) {
        float* pp = part + base + (size_t)o * 65536 + p;
        *(float4*)(pp)     = make_float4(acc[o][0], acc[o][1], acc[o][2], acc[o][3]);
        *(float4*)(pp + 4) = make_float4(acc[o][4], acc[o][5], acc[o][6], acc[o][7]);
    }
}

// ---------------- kernel F2: combine partials + grid + normalize -> vgrid ----------------
__global__ void kcomb(const float* __restrict__ part, float* __restrict__ vg) {
    int gid = blockIdx.x * 256 + threadIdx.x;  // 131072
    int n = gid >> 16, p = gid & 65535;
    float s0 = 0.f, s1 = 0.f, s2 = 0.f;
    for (int s = 0; s < 16; ++s) {
        const float* bp = part + ((size_t)(s * 2 + n)) * 3 * 65536 + p;
        s0 += bp[0];
        s1 += bp[65536];
        s2 += bp[131072];
    }
    int w = p & 63, h = (p >> 6) & 63, d = p >> 12;
    size_t vb = (size_t)n * 3 * 65536;
    vg[vb + p]          = ((float)w + s0) * (1.0f / 64.0f);
    vg[vb + 65536 + p]  = ((float)h + s1) * (1.0f / 64.0f);
    vg[vb + 131072 + p] = ((float)d + s2) * (1.0f / 16.0f);
}

// ---------------- kernel T: transpose y -> channel-last yt [n][8192][128] ----------------
__global__ __launch_bounds__(256) void ktrans(const float* __restrict__ y,
                                              float* __restrict__ yt) {
    int b = blockIdx.x;       // 512
    int n = b >> 8;
    int rem = b & 255;        // 2 c-tiles * 128 s-tiles
    int ct = rem >> 7, st = rem & 127;
    int c0 = ct * 64, s0 = st * 64;
    __shared__ float t[64][65];
    int tx = threadIdx.x & 63, ty = threadIdx.x >> 6;  // 4 rows/pass
#pragma unroll
    for (int k = 0; k < 16; ++k)
        t[ty + 4 * k][tx] = y[((size_t)(n * 128 + c0 + ty + 4 * k)) * 8192 + s0 + tx];
    __syncthreads();
#pragma unroll
    for (int k = 0; k < 16; ++k)
        yt[((size_t)(n * 8192 + s0 + ty + 4 * k)) * 128 + c0 + tx] = t[tx][ty + 4 * k];
}

// ---------------- kernel G: grid_sample, channel-last gathers ----------------
__global__ __launch_bounds__(256) void ksample(const float* __restrict__ yt,
                                               const float* __restrict__ vg,
                                               float* __restrict__ out) {
    const int b = blockIdx.x;        // 2048
    const int n = b >> 10;
    const int p0 = (b & 1023) << 6;  // 64 points per block
    const int tid = threadIdx.x;
    const int lane = tid & 63;
    const int wv = tid >> 6;         // 0..3

    __shared__ float lds[128 * 65];  // [c][pt], pad 65

    const float* ytn = yt + (size_t)n * 8192 * 128;
    const size_t vb = (size_t)n * 3 * 65536;

    for (int q = 0; q < 16; ++q) {
        const int pt = wv * 16 + q;  // 0..63, wave-uniform
        const int p = p0 + pt;
        float gx = vg[vb + p], gy = vg[vb + 65536 + p], gz = vg[vb + 131072 + p];
        float ix = ((gx + 1.f) * 32.f - 1.f) * 0.5f;
        float iy = ((gy + 1.f) * 32.f - 1.f) * 0.5f;
        float iz = ((gz + 1.f) * 8.f - 1.f) * 0.5f;
        int x0 = (int)floorf(ix), y0 = (int)floorf(iy), z0 = (int)floorf(iz);
        float fx = ix - (float)x0, fy = iy - (float)y0, fz = iz - (float)z0;
        float wx[2] = {1.f - fx, fx}, wy[2] = {1.f - fy, fy}, wz[2] = {1.f - fz, fz};
        int idx8[8];
        float w8[8];
        float wsum = 0.f;
#pragma unroll
        for (int k = 0; k < 8; ++k) {
            int dz = k >> 2, dy = (k >> 1) & 1, dx = k & 1;
            int zc = z0 + dz, yc = y0 + dy, xc = x0 + dx;
            bool valid = ((unsigned)zc < 8u) && ((unsigned)yc < 32u) && ((unsigned)xc < 32u);
            int zcl = min(max(zc, 0), 7), ycl = min(max(yc, 0), 31), xcl = min(max(xc, 0), 31);
            idx8[k] = (zcl * 32 + ycl) * 32 + xcl;
            float wgt = wz[dz] * wy[dy] * wx[dx];
            w8[k] = valid ? wgt : 0.f;
            wsum += w8[k];
        }
        float ax = 0.f, ay = 0.f;
        if (wsum != 0.f) {
#pragma unroll
            for (int k = 0; k < 8; ++k) {
                const float2 v = *(const float2*)(ytn + (size_t)idx8[k] * 128 + 2 * lane);
                ax = fmaf(w8[k], v.x, ax);
                ay = fmaf(w8[k], v.y, ay);
            }
        }
        lds[(2 * lane) * 65 + pt] = ax;
        lds[(2 * lane + 1) * 65 + pt] = ay;
    }
    __syncthreads();
    // coalesced store: 128 channel-rows of 64 points
    const int pw = tid & 63, cw = tid >> 6;
    float* ob = out + (size_t)n * 128 * 65536 + p0 + pw;
#pragma unroll
    for (int k = 0; k < 32; ++k) {
        int c = k * 4 + cw;
        ob[(size_t)c * 65536] = lds[c * 65 + pw];
    }
}

extern "C" void kernel_launch(void* const* d_in, const int* in_sizes, int n_in,
                              void* d_out, int out_size, void* d_ws, size_t ws_size,
                              hipStream_t stream) {
    const float* x     = (const float*)d_in[0];
    const float* y     = (const float*)d_in[1];
    const float* wdh   = (const float*)d_in[2];
    const float* wdl   = (const float*)d_in[3];
    const float* wflow = (const float*)d_in[4];
    const float* watt  = (const float*)d_in[5];
    const float* wconv = (const float*)d_in[6];
    float* out = (float*)d_out;

    float* ws     = (float*)d_ws;
    float* meanx  = ws;                   // 128
    float* wcombT = meanx + 128;          // 8192
    float* hf     = wcombT + 8192;        // 1048576
    float* low2   = hf + 1048576;         // 8388608
    float* hfup   = low2 + 8388608;       // 8388608
    float* vg     = hfup + 8388608;       // 393216

    // partials live in d_out (16*2*3*65536 = 6.29M floats <= 16.77M);
    // fully written by kflowp before kcomb reads; ksample overwrites all of d_out.
    float* part = out;
    // yt (2.1M floats) reuses the hfup region — hfup is dead after kflowp.
    float* yt = hfup;

    kmean<<<128, 256, 0, stream>>>(x, meanx);
    kprep<<<2, 64, 0, stream>>>(wdl, watt, wconv, meanx, wcombT);
    kconv1l<<<512, 256, 0, stream>>>(x, wcombT, low2);
    kconvh<<<64, 256, 0, stream>>>(y, wdh, hf);
    kups<<<32768, 256, 0, stream>>>(hf, hfup);
    kflowp<<<1024, 256, 0, stream>>>(hfup, low2, wflow, part);
    kcomb<<<512, 256, 0, stream>>>(part, vg);
    ktrans<<<512, 256, 0, stream>>>(y, yt);      // after kflowp: hfup region now free
    ksample<<<2048, 256, 0, stream>>>(yt, vg, out);
}

// Round 10
// 230.049 us; speedup vs baseline: 1.2919x; 1.0396x over previous
//
#include <hip/hip_runtime.h>
#include <math.h>

// x [2,64,16,64,64], y [2,128,8,32,32]
// w_down_h [64,128], w_down_l [64,64], w_flow [3,128,3,3,3],
// w_att_atten [64,64], w_att_conv [64,64]
// out = grid_sample(y, vgrid) -> [2,128,16,64,64] fp32

// ---------------- kernel A: per-channel mean of x ----------------
__global__ void kmean(const float* __restrict__ x, float* __restrict__ meanx) {
    int ch = blockIdx.x;  // 0..127  (n*64+c)
    const float4* base = (const float4*)(x + (size_t)ch * 65536);
    float s = 0.f;
    for (int j = threadIdx.x; j < 16384; j += 256) {
        float4 v = base[j];
        s += v.x + v.y + v.z + v.w;
    }
    __shared__ float red[256];
    red[threadIdx.x] = s;
    __syncthreads();
    for (int off = 128; off > 0; off >>= 1) {
        if (threadIdx.x < off) red[threadIdx.x] += red[threadIdx.x + off];
        __syncthreads();
    }
    if (threadIdx.x == 0) meanx[ch] = red[0] * (1.0f / 65536.0f);
}

// ---------------- kernel B: build W_comb^T per batch ----------------
__global__ void kprep(const float* __restrict__ wdl, const float* __restrict__ watt,
                      const float* __restrict__ wconv, const float* __restrict__ meanx,
                      float* __restrict__ wcombT) {
    int n = blockIdx.x;
    int c = threadIdx.x;  // 64 threads
    __shared__ float pooled[64], sc[64];
    float p = 0.f;
    for (int i = 0; i < 64; ++i) p += wdl[c * 64 + i] * meanx[n * 64 + i];
    pooled[c] = p;
    __syncthreads();
    float a = 0.f;
    for (int i = 0; i < 64; ++i) a += watt[c * 64 + i] * pooled[i];
    sc[c] = 1.f + 1.f / (1.f + expf(-a));
    __syncthreads();
    int o = c;
    for (int i = 0; i < 64; ++i) {
        float acc = 0.f;
        for (int j = 0; j < 64; ++j) acc += wconv[o * 64 + j] * sc[j] * wdl[j * 64 + i];
        wcombT[n * 4096 + i * 64 + o] = acc;
    }
}

// ---------------- kernel C: low2 = W_comb * x  (scalar weights, no LDS) ----------------
// 2 output-splits x 32 outputs; 2 points/thread. Weights via wave-uniform
// addresses -> s_load; FMAs take the SGPR operand directly. Zero DS traffic.
__global__ __launch_bounds__(256) void kconv1l(const float* __restrict__ x,
                                               const float* __restrict__ wcombT,
                                               float* __restrict__ low2) {
    const int b = blockIdx.x;   // 512
    const int n = b >> 8;
    const int r = b & 255;
    const int os = r & 1;       // 32 outputs each
    const int tile = r >> 1;    // 0..127, 512 points
    const int p = tile * 512 + 2 * threadIdx.x;
    const float* xb = x + (size_t)n * 64 * 65536 + p;
    const float* wr = wcombT + n * 4096 + os * 32;  // [i][o] stride 64 — uniform

    float2 acc[32];
#pragma unroll
    for (int o = 0; o < 32; ++o) acc[o] = make_float2(0.f, 0.f);

    for (int i = 0; i < 64; i += 2) {
        const float2 xi0 = *(const float2*)(xb + (size_t)(i + 0) * 65536);
        const float2 xi1 = *(const float2*)(xb + (size_t)(i + 1) * 65536);
#pragma unroll
        for (int o = 0; o < 32; ++o) {
            const float w0 = wr[(i + 0) * 64 + o];
            const float w1 = wr[(i + 1) * 64 + o];
            acc[o].x = fmaf(w0, xi0.x, acc[o].x);
            acc[o].y = fmaf(w0, xi0.y, acc[o].y);
            acc[o].x = fmaf(w1, xi1.x, acc[o].x);
            acc[o].y = fmaf(w1, xi1.y, acc[o].y);
        }
    }
    float* ob = low2 + (size_t)(n * 64 + os * 32) * 65536 + p;
#pragma unroll
    for (int o = 0; o < 32; ++o)
        *(float2*)(ob + (size_t)o * 65536) = acc[o];
}

// ---------------- kernel D: hf = w_down_h * y  (scalar weights, no LDS) ----------------
__global__ __launch_bounds__(256) void kconvh(const float* __restrict__ y,
                                              const float* __restrict__ wdh,
                                              float* __restrict__ hf) {
    const int b = blockIdx.x;   // 128
    const int n = b >> 6;
    const int r = b & 63;
    const int os = r & 3;       // 16 outputs each
    const int tile = r >> 2;    // 0..15, 512 points
    const int p = tile * 512 + 2 * threadIdx.x;
    const float* yb = y + (size_t)n * 128 * 8192 + p;

    float2 acc[16];
#pragma unroll
    for (int o = 0; o < 16; ++o) acc[o] = make_float2(0.f, 0.f);

    for (int i = 0; i < 128; i += 2) {
        const float2 yi0 = *(const float2*)(yb + (size_t)(i + 0) * 8192);
        const float2 yi1 = *(const float2*)(yb + (size_t)(i + 1) * 8192);
#pragma unroll
        for (int o = 0; o < 16; ++o) {
            const float w0 = wdh[(os * 16 + o) * 128 + i + 0];
            const float w1 = wdh[(os * 16 + o) * 128 + i + 1];
            acc[o].x = fmaf(w0, yi0.x, acc[o].x);
            acc[o].y = fmaf(w0, yi0.y, acc[o].y);
            acc[o].x = fmaf(w1, yi1.x, acc[o].x);
            acc[o].y = fmaf(w1, yi1.y, acc[o].y);
        }
    }
    float* ob = hf + (size_t)(n * 64 + os * 16) * 8192 + p;
#pragma unroll
    for (int o = 0; o < 16; ++o)
        *(float2*)(ob + (size_t)o * 8192) = acc[o];
}

// ---------------- kernel E: trilinear upsample (align_corners=True) ----------------
__global__ void kups(const float* __restrict__ hf, float* __restrict__ hfup) {
    int idx = blockIdx.x * 256 + threadIdx.x;  // 8388608 total
    int w = idx & 63, h = (idx >> 6) & 63, d = (idx >> 12) & 15;
    int c = (idx >> 16) & 63, n = idx >> 22;
    const float SD = 7.0f / 15.0f, SH = 31.0f / 63.0f;
    float pd = (float)d * SD, ph = (float)h * SH, pw = (float)w * SH;
    int z0 = (int)pd; if (z0 > 7) z0 = 7;
    int z1 = min(z0 + 1, 7); float fz = pd - (float)z0;
    int y0 = (int)ph; if (y0 > 31) y0 = 31;
    int y1 = min(y0 + 1, 31); float fy = ph - (float)y0;
    int x0 = (int)pw; if (x0 > 31) x0 = 31;
    int x1 = min(x0 + 1, 31); float fx = pw - (float)x0;
    const float* b = hf + (size_t)(n * 64 + c) * 8192;
    float v000 = b[(z0 * 32 + y0) * 32 + x0], v001 = b[(z0 * 32 + y0) * 32 + x1];
    float v010 = b[(z0 * 32 + y1) * 32 + x0], v011 = b[(z0 * 32 + y1) * 32 + x1];
    float v100 = b[(z1 * 32 + y0) * 32 + x0], v101 = b[(z1 * 32 + y0) * 32 + x1];
    float v110 = b[(z1 * 32 + y1) * 32 + x0], v111 = b[(z1 * 32 + y1) * 32 + x1];
    float c00 = v000 + (v001 - v000) * fx;
    float c01 = v010 + (v011 - v010) * fx;
    float c10 = v100 + (v101 - v100) * fx;
    float c11 = v110 + (v111 - v110) * fx;
    float c0 = c00 + (c01 - c00) * fy;
    float c1 = c10 + (c11 - c10) * fy;
    hfup[idx] = c0 + (c1 - c0) * fz;
}

// ---------------- kernel F: 3x3x3 conv partials — wave-independent tiles, ZERO barriers ----------------
// Global wave id g: split = g&15 (8 channels), tile = g>>4 (4z x 8y x 16x per WAVE).
// Each wave stages its own [6][10][18] halo window into private LDS (single buffer —
// same-wave DS ops are in-order, no __syncthreads anywhere). Split-staging: next
// channel's 17 global loads issue before the 648-FMA compute. Weights scalarized
// via readfirstlane. part layout: part[((split*2 + n)*3 + o)*65536 + p], 16 splits.
__global__ __launch_bounds__(256) void kflowp(const float* __restrict__ hfup,
                                              const float* __restrict__ low2,
                                              const float* __restrict__ wflow,
                                              float* __restrict__ part) {
    const int wv = threadIdx.x >> 6;
    const int lane = threadIdx.x & 63;
    const int g = blockIdx.x * 4 + wv;   // 0..4095
    const int split = g & 15;
    const int t = g >> 4;                // 0..255
    const int n = t >> 7;
    const int td = (t >> 5) & 3, th = (t >> 2) & 7, twx = t & 3;
    const int d0 = td * 4, h0 = th * 8, w0 = twx * 16;
    const int xo = lane & 1;             // 2 x-groups of 8 outputs
    const int ly = (lane >> 1) & 7;      // 8 y rows
    const int lz = lane >> 4;            // 4 z planes

    __shared__ float lds[4][1088];       // per-wave private [6][10][18] window
    float* buf = lds[wv];

    // one-time staging map: element e = lane + 64k -> global offset (or -1)
    int goff[17];
#pragma unroll
    for (int k = 0; k < 17; ++k) {
        const int e = lane + 64 * k;
        const int r = e / 18;            // row 0..59
        const int lx = e - r * 18;
        const int z = r / 10;
        const int yy = r - z * 10;
        const int gz = d0 - 1 + z, gy = h0 - 1 + yy, gx = w0 - 1 + lx;
        const bool ok = (e < 1080) && ((unsigned)gz < 16u) && ((unsigned)gy < 64u) &&
                        ((unsigned)gx < 64u);
        goff[k] = ok ? (gz * 4096 + gy * 64 + gx) : -1;
    }

    const float* srcb = (split < 8)
        ? hfup + (size_t)(n * 64 + split * 8) * 65536
        : low2 + (size_t)(n * 64 + (split - 8) * 8) * 65536;

    float acc[3][8];
#pragma unroll
    for (int o = 0; o < 3; ++o)
#pragma unroll
        for (int j = 0; j < 8; ++j) acc[o][j] = 0.f;

    // stage channel 0 (same-wave DS ordering; no barrier)
#pragma unroll
    for (int k = 0; k < 17; ++k) {
        const int e = lane + 64 * k;
        if (e < 1080) buf[e] = (goff[k] >= 0) ? srcb[goff[k]] : 0.f;
    }

    for (int ci = 0; ci < 8; ++ci) {
        // split-stage: issue next channel's loads first (hide under FMA)
        float stg[17];
        if (ci < 7) {
            const float* src = srcb + (size_t)(ci + 1) * 65536;
#pragma unroll
            for (int k = 0; k < 17; ++k)
                stg[k] = (goff[k] >= 0) ? src[goff[k]] : 0.f;
        }
        const int cgs = __builtin_amdgcn_readfirstlane(split * 8 + ci);
        const float* wb = wflow + (size_t)cgs * 27;   // SGPR base -> s_loads
#pragma unroll
        for (int dz = 0; dz < 3; ++dz) {
#pragma unroll
            for (int dy = 0; dy < 3; ++dy) {
                const float* rp = &buf[((lz + dz) * 10 + ly + dy) * 18 + 8 * xo];
                const float2 a0 = *(const float2*)(rp);
                const float2 a1 = *(const float2*)(rp + 2);
                const float2 a2 = *(const float2*)(rp + 4);
                const float2 a3 = *(const float2*)(rp + 6);
                const float2 a4 = *(const float2*)(rp + 8);
                const float v[10] = {a0.x, a0.y, a1.x, a1.y, a2.x,
                                     a2.y, a3.x, a3.y, a4.x, a4.y};
                float wq[3][3];
#pragma unroll
                for (int o = 0; o < 3; ++o)
#pragma unroll
                    for (int dx = 0; dx < 3; ++dx)
                        wq[o][dx] = wb[o * 3456 + (dz * 3 + dy) * 3 + dx];
#pragma unroll
                for (int o = 0; o < 3; ++o)
#pragma unroll
                    for (int j = 0; j < 8; ++j)
#pragma unroll
                        for (int dx = 0; dx < 3; ++dx)
                            acc[o][j] = fmaf(wq[o][dx], v[j + dx], acc[o][j]);
            }
        }
        // write staged channel into the (single) buffer — same-wave in-order DS
        if (ci < 7) {
#pragma unroll
            for (int k = 0; k < 17; ++k) {
                const int e = lane + 64 * k;
                if (e < 1080) buf[e] = stg[k];
            }
        }
    }

    const int oz = d0 + lz, oy = h0 + ly, ox = w0 + 8 * xo;
    const size_t base = ((size_t)(split * 2 + n)) * 3 * 65536;
    const int p = oz * 4096 + oy * 64 + ox;
#pragma unroll
    for (int o = 0; o < 3; ++o) {
        float* pp = part + base + (size_t)o * 65536 + p;
        *(float4*)(pp)     = make_float4(acc[o][0], acc[o][1], acc[o][2], acc[o][3]);
        *(float4*)(pp + 4) = make_float4(acc[o][4], acc[o][5], acc[o][6], acc[o][7]);
    }
}

// ---------------- kernel F2: combine partials + grid + normalize -> vgrid ----------------
__global__ void kcomb(const float* __restrict__ part, float* __restrict__ vg) {
    int gid = blockIdx.x * 256 + threadIdx.x;  // 131072
    int n = gid >> 16, p = gid & 65535;
    float s0 = 0.f, s1 = 0.f, s2 = 0.f;
    for (int s = 0; s < 16; ++s) {
        const float* bp = part + ((size_t)(s * 2 + n)) * 3 * 65536 + p;
        s0 += bp[0];
        s1 += bp[65536];
        s2 += bp[131072];
    }
    int w = p & 63, h = (p >> 6) & 63, d = p >> 12;
    size_t vb = (size_t)n * 3 * 65536;
    vg[vb + p]          = ((float)w + s0) * (1.0f / 64.0f);
    vg[vb + 65536 + p]  = ((float)h + s1) * (1.0f / 64.0f);
    vg[vb + 131072 + p] = ((float)d + s2) * (1.0f / 16.0f);
}

// ---------------- kernel T: transpose y -> channel-last yt [n][8192][128] ----------------
__global__ __launch_bounds__(256) void ktrans(const float* __restrict__ y,
                                              float* __restrict__ yt) {
    int b = blockIdx.x;       // 512
    int n = b >> 8;
    int rem = b & 255;        // 2 c-tiles * 128 s-tiles
    int ct = rem >> 7, st = rem & 127;
    int c0 = ct * 64, s0 = st * 64;
    __shared__ float t[64][65];
    int tx = threadIdx.x & 63, ty = threadIdx.x >> 6;  // 4 rows/pass
#pragma unroll
    for (int k = 0; k < 16; ++k)
        t[ty + 4 * k][tx] = y[((size_t)(n * 128 + c0 + ty + 4 * k)) * 8192 + s0 + tx];
    __syncthreads();
#pragma unroll
    for (int k = 0; k < 16; ++k)
        yt[((size_t)(n * 8192 + s0 + ty + 4 * k)) * 128 + c0 + tx] = t[tx][ty + 4 * k];
}

// ---------------- kernel G: grid_sample, channel-last gathers ----------------
__global__ __launch_bounds__(256) void ksample(const float* __restrict__ yt,
                                               const float* __restrict__ vg,
                                               float* __restrict__ out) {
    const int b = blockIdx.x;        // 2048
    const int n = b >> 10;
    const int p0 = (b & 1023) << 6;  // 64 points per block
    const int tid = threadIdx.x;
    const int lane = tid & 63;
    const int wv = tid >> 6;         // 0..3

    __shared__ float lds[128 * 65];  // [c][pt], pad 65

    const float* ytn = yt + (size_t)n * 8192 * 128;
    const size_t vb = (size_t)n * 3 * 65536;

    for (int q = 0; q < 16; ++q) {
        const int pt = wv * 16 + q;  // 0..63, wave-uniform
        const int p = p0 + pt;
        float gx = vg[vb + p], gy = vg[vb + 65536 + p], gz = vg[vb + 131072 + p];
        float ix = ((gx + 1.f) * 32.f - 1.f) * 0.5f;
        float iy = ((gy + 1.f) * 32.f - 1.f) * 0.5f;
        float iz = ((gz + 1.f) * 8.f - 1.f) * 0.5f;
        int x0 = (int)floorf(ix), y0 = (int)floorf(iy), z0 = (int)floorf(iz);
        float fx = ix - (float)x0, fy = iy - (float)y0, fz = iz - (float)z0;
        float wx[2] = {1.f - fx, fx}, wy[2] = {1.f - fy, fy}, wz[2] = {1.f - fz, fz};
        int idx8[8];
        float w8[8];
        float wsum = 0.f;
#pragma unroll
        for (int k = 0; k < 8; ++k) {
            int dz = k >> 2, dy = (k >> 1) & 1, dx = k & 1;
            int zc = z0 + dz, yc = y0 + dy, xc = x0 + dx;
            bool valid = ((unsigned)zc < 8u) && ((unsigned)yc < 32u) && ((unsigned)xc < 32u);
            int zcl = min(max(zc, 0), 7), ycl = min(max(yc, 0), 31), xcl = min(max(xc, 0), 31);
            idx8[k] = (zcl * 32 + ycl) * 32 + xcl;
            float wgt = wz[dz] * wy[dy] * wx[dx];
            w8[k] = valid ? wgt : 0.f;
            wsum += w8[k];
        }
        float ax = 0.f, ay = 0.f;
        if (wsum != 0.f) {
#pragma unroll
            for (int k = 0; k < 8; ++k) {
                const float2 v = *(const float2*)(ytn + (size_t)idx8[k] * 128 + 2 * lane);
                ax = fmaf(w8[k], v.x, ax);
                ay = fmaf(w8[k], v.y, ay);
            }
        }
        lds[(2 * lane) * 65 + pt] = ax;
        lds[(2 * lane + 1) * 65 + pt] = ay;
    }
    __syncthreads();
    // coalesced store: 128 channel-rows of 64 points
    const int pw = tid & 63, cw = tid >> 6;
    float* ob = out + (size_t)n * 128 * 65536 + p0 + pw;
#pragma unroll
    for (int k = 0; k < 32; ++k) {
        int c = k * 4 + cw;
        ob[(size_t)c * 65536] = lds[c * 65 + pw];
    }
}

extern "C" void kernel_launch(void* const* d_in, const int* in_sizes, int n_in,
                              void* d_out, int out_size, void* d_ws, size_t ws_size,
                              hipStream_t stream) {
    const float* x     = (const float*)d_in[0];
    const float* y     = (const float*)d_in[1];
    const float* wdh   = (const float*)d_in[2];
    const float* wdl   = (const float*)d_in[3];
    const float* wflow = (const float*)d_in[4];
    const float* watt  = (const float*)d_in[5];
    const float* wconv = (const float*)d_in[6];
    float* out = (float*)d_out;

    float* ws     = (float*)d_ws;
    float* meanx  = ws;                   // 128
    float* wcombT = meanx + 128;          // 8192
    float* hf     = wcombT + 8192;        // 1048576
    float* low2   = hf + 1048576;         // 8388608
    float* hfup   = low2 + 8388608;       // 8388608
    float* vg     = hfup + 8388608;       // 393216

    // partials live in d_out (16*2*3*65536 = 6.29M floats <= 16.77M);
    // fully written by kflowp before kcomb reads; ksample overwrites all of d_out.
    float* part = out;
    // yt (2.1M floats) reuses the hfup region — hfup is dead after kflowp.
    float* yt = hfup;

    kmean<<<128, 256, 0, stream>>>(x, meanx);
    kprep<<<2, 64, 0, stream>>>(wdl, watt, wconv, meanx, wcombT);
    kconv1l<<<512, 256, 0, stream>>>(x, wcombT, low2);
    kconvh<<<128, 256, 0, stream>>>(y, wdh, hf);
    kups<<<32768, 256, 0, stream>>>(hf, hfup);
    kflowp<<<1024, 256, 0, stream>>>(hfup, low2, wflow, part);
    kcomb<<<512, 256, 0, stream>>>(part, vg);
    ktrans<<<512, 256, 0, stream>>>(y, yt);      // after kflowp: hfup region now free
    ksample<<<2048, 256, 0, stream>>>(yt, vg, out);
}

// Round 11
// 221.874 us; speedup vs baseline: 1.3395x; 1.0368x over previous
//
#include <hip/hip_runtime.h>
#include <math.h>

// x [2,64,16,64,64], y [2,128,8,32,32]
// w_down_h [64,128], w_down_l [64,64], w_flow [3,128,3,3,3],
// w_att_atten [64,64], w_att_conv [64,64]
// out = grid_sample(y, vgrid) -> [2,128,16,64,64] fp32

// ---------------- kernel A: per-channel mean of x ----------------
__global__ void kmean(const float* __restrict__ x, float* __restrict__ meanx) {
    int ch = blockIdx.x;  // 0..127  (n*64+c)
    const float4* base = (const float4*)(x + (size_t)ch * 65536);
    float s = 0.f;
    for (int j = threadIdx.x; j < 16384; j += 256) {
        float4 v = base[j];
        s += v.x + v.y + v.z + v.w;
    }
    __shared__ float red[256];
    red[threadIdx.x] = s;
    __syncthreads();
    for (int off = 128; off > 0; off >>= 1) {
        if (threadIdx.x < off) red[threadIdx.x] += red[threadIdx.x + off];
        __syncthreads();
    }
    if (threadIdx.x == 0) meanx[ch] = red[0] * (1.0f / 65536.0f);
}

// ---------------- kernel B: build W_comb^T per batch (parallel, LDS, conflict-free) ----------------
// W_comb[o,i] = sum_j wconv[o,j] * (1+sigmoid(a[j])) * wdl[j,i]; stored wcombT[n][i][o].
__global__ __launch_bounds__(256) void kprep(const float* __restrict__ wdl,
                                             const float* __restrict__ watt,
                                             const float* __restrict__ wconv,
                                             const float* __restrict__ meanx,
                                             float* __restrict__ wcombT) {
    const int n = blockIdx.x;   // 2
    const int tid = threadIdx.x;
    __shared__ float s_wdl[4096];   // wdl[j][i] as-is
    __shared__ float s_wcT[4096];   // wconv transposed: [j][o]
    __shared__ float pooled[64], sc[64];
    for (int k = tid; k < 4096; k += 256) {
        s_wdl[k] = wdl[k];
        int o = k >> 6, j = k & 63;
        s_wcT[j * 64 + o] = wconv[k];
    }
    __syncthreads();
    if (tid < 64) {
        float p = 0.f;
        for (int i = 0; i < 64; ++i) p += s_wdl[tid * 64 + i] * meanx[n * 64 + i];
        pooled[tid] = p;
    }
    __syncthreads();
    if (tid < 64) {
        float a = 0.f;
        for (int i = 0; i < 64; ++i) a += watt[tid * 64 + i] * pooled[i];
        sc[tid] = 1.f + 1.f / (1.f + expf(-a));
    }
    __syncthreads();
    // 16 outputs/thread: idx = tid+256k; o = idx&63 (lane-consecutive), i = idx>>6 (broadcast)
    for (int k = 0; k < 16; ++k) {
        const int idx = tid + 256 * k;
        const int o = idx & 63, i = idx >> 6;
        float acc = 0.f;
#pragma unroll 8
        for (int j = 0; j < 64; ++j)
            acc += s_wcT[j * 64 + o] * (sc[j] * s_wdl[j * 64 + i]);
        wcombT[n * 4096 + i * 64 + o] = acc;
    }
}

// ---------------- kernel C: low2 = W_comb * x  (scalar weights, no LDS) ----------------
__global__ __launch_bounds__(256) void kconv1l(const float* __restrict__ x,
                                               const float* __restrict__ wcombT,
                                               float* __restrict__ low2) {
    const int b = blockIdx.x;   // 512
    const int n = b >> 8;
    const int r = b & 255;
    const int os = r & 1;       // 32 outputs each
    const int tile = r >> 1;    // 0..127, 512 points
    const int p = tile * 512 + 2 * threadIdx.x;
    const float* xb = x + (size_t)n * 64 * 65536 + p;
    const float* wr = wcombT + n * 4096 + os * 32;  // [i][o] stride 64 — uniform

    float2 acc[32];
#pragma unroll
    for (int o = 0; o < 32; ++o) acc[o] = make_float2(0.f, 0.f);

    for (int i = 0; i < 64; i += 2) {
        const float2 xi0 = *(const float2*)(xb + (size_t)(i + 0) * 65536);
        const float2 xi1 = *(const float2*)(xb + (size_t)(i + 1) * 65536);
#pragma unroll
        for (int o = 0; o < 32; ++o) {
            const float w0 = wr[(i + 0) * 64 + o];
            const float w1 = wr[(i + 1) * 64 + o];
            acc[o].x = fmaf(w0, xi0.x, acc[o].x);
            acc[o].y = fmaf(w0, xi0.y, acc[o].y);
            acc[o].x = fmaf(w1, xi1.x, acc[o].x);
            acc[o].y = fmaf(w1, xi1.y, acc[o].y);
        }
    }
    float* ob = low2 + (size_t)(n * 64 + os * 32) * 65536 + p;
#pragma unroll
    for (int o = 0; o < 32; ++o)
        *(float2*)(ob + (size_t)o * 65536) = acc[o];
}

// ---------------- kernel D: hf = w_down_h * y  (scalar weights, no LDS) ----------------
__global__ __launch_bounds__(256) void kconvh(const float* __restrict__ y,
                                              const float* __restrict__ wdh,
                                              float* __restrict__ hf) {
    const int b = blockIdx.x;   // 128
    const int n = b >> 6;
    const int r = b & 63;
    const int os = r & 3;       // 16 outputs each
    const int tile = r >> 2;    // 0..15, 512 points
    const int p = tile * 512 + 2 * threadIdx.x;
    const float* yb = y + (size_t)n * 128 * 8192 + p;

    float2 acc[16];
#pragma unroll
    for (int o = 0; o < 16; ++o) acc[o] = make_float2(0.f, 0.f);

    for (int i = 0; i < 128; i += 2) {
        const float2 yi0 = *(const float2*)(yb + (size_t)(i + 0) * 8192);
        const float2 yi1 = *(const float2*)(yb + (size_t)(i + 1) * 8192);
#pragma unroll
        for (int o = 0; o < 16; ++o) {
            const float w0 = wdh[(os * 16 + o) * 128 + i + 0];
            const float w1 = wdh[(os * 16 + o) * 128 + i + 1];
            acc[o].x = fmaf(w0, yi0.x, acc[o].x);
            acc[o].y = fmaf(w0, yi0.y, acc[o].y);
            acc[o].x = fmaf(w1, yi1.x, acc[o].x);
            acc[o].y = fmaf(w1, yi1.y, acc[o].y);
        }
    }
    float* ob = hf + (size_t)(n * 64 + os * 16) * 8192 + p;
#pragma unroll
    for (int o = 0; o < 16; ++o)
        *(float2*)(ob + (size_t)o * 8192) = acc[o];
}

// ---------------- kernel E: trilinear upsample (align_corners=True) ----------------
__global__ void kups(const float* __restrict__ hf, float* __restrict__ hfup) {
    int idx = blockIdx.x * 256 + threadIdx.x;  // 8388608 total
    int w = idx & 63, h = (idx >> 6) & 63, d = (idx >> 12) & 15;
    int c = (idx >> 16) & 63, n = idx >> 22;
    const float SD = 7.0f / 15.0f, SH = 31.0f / 63.0f;
    float pd = (float)d * SD, ph = (float)h * SH, pw = (float)w * SH;
    int z0 = (int)pd; if (z0 > 7) z0 = 7;
    int z1 = min(z0 + 1, 7); float fz = pd - (float)z0;
    int y0 = (int)ph; if (y0 > 31) y0 = 31;
    int y1 = min(y0 + 1, 31); float fy = ph - (float)y0;
    int x0 = (int)pw; if (x0 > 31) x0 = 31;
    int x1 = min(x0 + 1, 31); float fx = pw - (float)x0;
    const float* b = hf + (size_t)(n * 64 + c) * 8192;
    float v000 = b[(z0 * 32 + y0) * 32 + x0], v001 = b[(z0 * 32 + y0) * 32 + x1];
    float v010 = b[(z0 * 32 + y1) * 32 + x0], v011 = b[(z0 * 32 + y1) * 32 + x1];
    float v100 = b[(z1 * 32 + y0) * 32 + x0], v101 = b[(z1 * 32 + y0) * 32 + x1];
    float v110 = b[(z1 * 32 + y1) * 32 + x0], v111 = b[(z1 * 32 + y1) * 32 + x1];
    float c00 = v000 + (v001 - v000) * fx;
    float c01 = v010 + (v011 - v010) * fx;
    float c10 = v100 + (v101 - v100) * fx;
    float c11 = v110 + (v111 - v110) * fx;
    float c0 = c00 + (c01 - c00) * fy;
    float c1 = c10 + (c11 - c10) * fy;
    hfup[idx] = c0 + (c1 - c0) * fz;
}

// ---------------- kernel F: 3x3x3 conv partials — wave-independent, stride-20 window ----------------
// Wave-private [6][10][20] LDS window (cols 18-19 junk, never read). Row stride 20:
// b64 start banks are multiples of 4 -> worst-case 2-way (free). Zero barriers.
__global__ __launch_bounds__(256) void kflowp(const float* __restrict__ hfup,
                                              const float* __restrict__ low2,
                                              const float* __restrict__ wflow,
                                              float* __restrict__ part) {
    const int wv = threadIdx.x >> 6;
    const int lane = threadIdx.x & 63;
    const int g = blockIdx.x * 4 + wv;   // 0..4095
    const int split = g & 15;
    const int t = g >> 4;                // 0..255
    const int n = t >> 7;
    const int td = (t >> 5) & 3, th = (t >> 2) & 7, twx = t & 3;
    const int d0 = td * 4, h0 = th * 8, w0 = twx * 16;
    const int xo = lane & 1;             // 2 x-groups of 8 outputs
    const int ly = (lane >> 1) & 7;      // 8 y rows
    const int lz = lane >> 4;            // 4 z planes

    __shared__ float lds[4][1200];       // per-wave private [6][10][20] window
    float* buf = lds[wv];

    // one-time staging map: element e = lane + 64k -> global offset (or -1)
    int goff[19];
#pragma unroll
    for (int k = 0; k < 19; ++k) {
        const int e = lane + 64 * k;
        const int r = e / 20;            // row 0..59
        const int lx = e - r * 20;
        const int z = r / 10;
        const int yy = r - z * 10;
        const int gz = d0 - 1 + z, gy = h0 - 1 + yy, gx = w0 - 1 + lx;
        const bool ok = (e < 1200) && ((unsigned)gz < 16u) && ((unsigned)gy < 64u) &&
                        ((unsigned)gx < 64u);
        goff[k] = ok ? (gz * 4096 + gy * 64 + gx) : -1;
    }

    const float* srcb = (split < 8)
        ? hfup + (size_t)(n * 64 + split * 8) * 65536
        : low2 + (size_t)(n * 64 + (split - 8) * 8) * 65536;

    float acc[3][8];
#pragma unroll
    for (int o = 0; o < 3; ++o)
#pragma unroll
        for (int j = 0; j < 8; ++j) acc[o][j] = 0.f;

    // stage channel 0 (same-wave DS ordering; no barrier)
#pragma unroll
    for (int k = 0; k < 19; ++k) {
        const int e = lane + 64 * k;
        if (e < 1200) buf[e] = (goff[k] >= 0) ? srcb[goff[k]] : 0.f;
    }

    for (int ci = 0; ci < 8; ++ci) {
        // split-stage: issue next channel's loads first (hide under FMA)
        float stg[19];
        if (ci < 7) {
            const float* src = srcb + (size_t)(ci + 1) * 65536;
#pragma unroll
            for (int k = 0; k < 19; ++k)
                stg[k] = (goff[k] >= 0) ? src[goff[k]] : 0.f;
        }
        const int cgs = __builtin_amdgcn_readfirstlane(split * 8 + ci);
        const float* wb = wflow + (size_t)cgs * 27;   // SGPR base -> s_loads
#pragma unroll
        for (int dz = 0; dz < 3; ++dz) {
#pragma unroll
            for (int dy = 0; dy < 3; ++dy) {
                const float* rp = &buf[((lz + dz) * 10 + ly + dy) * 20 + 8 * xo];
                const float2 a0 = *(const float2*)(rp);
                const float2 a1 = *(const float2*)(rp + 2);
                const float2 a2 = *(const float2*)(rp + 4);
                const float2 a3 = *(const float2*)(rp + 6);
                const float2 a4 = *(const float2*)(rp + 8);
                const float v[10] = {a0.x, a0.y, a1.x, a1.y, a2.x,
                                     a2.y, a3.x, a3.y, a4.x, a4.y};
                float wq[3][3];
#pragma unroll
                for (int o = 0; o < 3; ++o)
#pragma unroll
                    for (int dx = 0; dx < 3; ++dx)
                        wq[o][dx] = wb[o * 3456 + (dz * 3 + dy) * 3 + dx];
#pragma unroll
                for (int o = 0; o < 3; ++o)
#pragma unroll
                    for (int j = 0; j < 8; ++j)
#pragma unroll
                        for (int dx = 0; dx < 3; ++dx)
                            acc[o][j] = fmaf(wq[o][dx], v[j + dx], acc[o][j]);
            }
        }
        // write staged channel into the (single) buffer — same-wave in-order DS
        if (ci < 7) {
#pragma unroll
            for (int k = 0; k < 19; ++k) {
                const int e = lane + 64 * k;
                if (e < 1200) buf[e] = stg[k];
            }
        }
    }

    const int oz = d0 + lz, oy = h0 + ly, ox = w0 + 8 * xo;
    const size_t base = ((size_t)(split * 2 + n)) * 3 * 65536;
    const int p = oz * 4096 + oy * 64 + ox;
#pragma unroll
    for (int o = 0; o < 3; ++o) {
        float* pp = part + base + (size_t)o * 65536 + p;
        *(float4*)(pp)     = make_float4(acc[o][0], acc[o][1], acc[o][2], acc[o][3]);
        *(float4*)(pp + 4) = make_float4(acc[o][4], acc[o][5], acc[o][6], acc[o][7]);
    }
}

// ---------------- kernel F2: combine partials + grid + normalize -> vgrid ----------------
__global__ void kcomb(const float* __restrict__ part, float* __restrict__ vg) {
    int gid = blockIdx.x * 256 + threadIdx.x;  // 131072
    int n = gid >> 16, p = gid & 65535;
    float s0 = 0.f, s1 = 0.f, s2 = 0.f;
    for (int s = 0; s < 16; ++s) {
        const float* bp = part + ((size_t)(s * 2 + n)) * 3 * 65536 + p;
        s0 += bp[0];
        s1 += bp[65536];
        s2 += bp[131072];
    }
    int w = p & 63, h = (p >> 6) & 63, d = p >> 12;
    size_t vb = (size_t)n * 3 * 65536;
    vg[vb + p]          = ((float)w + s0) * (1.0f / 64.0f);
    vg[vb + 65536 + p]  = ((float)h + s1) * (1.0f / 64.0f);
    vg[vb + 131072 + p] = ((float)d + s2) * (1.0f / 16.0f);
}

// ---------------- kernel T: transpose y -> channel-last yt [n][8192][128] ----------------
__global__ __launch_bounds__(256) void ktrans(const float* __restrict__ y,
                                              float* __restrict__ yt) {
    int b = blockIdx.x;       // 512
    int n = b >> 8;
    int rem = b & 255;        // 2 c-tiles * 128 s-tiles
    int ct = rem >> 7, st = rem & 127;
    int c0 = ct * 64, s0 = st * 64;
    __shared__ float t[64][65];
    int tx = threadIdx.x & 63, ty = threadIdx.x >> 6;  // 4 rows/pass
#pragma unroll
    for (int k = 0; k < 16; ++k)
        t[ty + 4 * k][tx] = y[((size_t)(n * 128 + c0 + ty + 4 * k)) * 8192 + s0 + tx];
    __syncthreads();
#pragma unroll
    for (int k = 0; k < 16; ++k)
        yt[((size_t)(n * 8192 + s0 + ty + 4 * k)) * 128 + c0 + tx] = t[tx][ty + 4 * k];
}

// ---------------- kernel G: grid_sample, channel-last gathers ----------------
__global__ __launch_bounds__(256) void ksample(const float* __restrict__ yt,
                                               const float* __restrict__ vg,
                                               float* __restrict__ out) {
    const int b = blockIdx.x;        // 2048
    const int n = b >> 10;
    const int p0 = (b & 1023) << 6;  // 64 points per block
    const int tid = threadIdx.x;
    const int lane = tid & 63;
    const int wv = tid >> 6;         // 0..3

    __shared__ float lds[128 * 65];  // [c][pt], pad 65

    const float* ytn = yt + (size_t)n * 8192 * 128;
    const size_t vb = (size_t)n * 3 * 65536;

    for (int q = 0; q < 16; ++q) {
        const int pt = wv * 16 + q;  // 0..63, wave-uniform
        const int p = p0 + pt;
        float gx = vg[vb + p], gy = vg[vb + 65536 + p], gz = vg[vb + 131072 + p];
        float ix = ((gx + 1.f) * 32.f - 1.f) * 0.5f;
        float iy = ((gy + 1.f) * 32.f - 1.f) * 0.5f;
        float iz = ((gz + 1.f) * 8.f - 1.f) * 0.5f;
        int x0 = (int)floorf(ix), y0 = (int)floorf(iy), z0 = (int)floorf(iz);
        float fx = ix - (float)x0, fy = iy - (float)y0, fz = iz - (float)z0;
        float wx[2] = {1.f - fx, fx}, wy[2] = {1.f - fy, fy}, wz[2] = {1.f - fz, fz};
        int idx8[8];
        float w8[8];
        float wsum = 0.f;
#pragma unroll
        for (int k = 0; k < 8; ++k) {
            int dz = k >> 2, dy = (k >> 1) & 1, dx = k & 1;
            int zc = z0 + dz, yc = y0 + dy, xc = x0 + dx;
            bool valid = ((unsigned)zc < 8u) && ((unsigned)yc < 32u) && ((unsigned)xc < 32u);
            int zcl = min(max(zc, 0), 7), ycl = min(max(yc, 0), 31), xcl = min(max(xc, 0), 31);
            idx8[k] = (zcl * 32 + ycl) * 32 + xcl;
            float wgt = wz[dz] * wy[dy] * wx[dx];
            w8[k] = valid ? wgt : 0.f;
            wsum += w8[k];
        }
        float ax = 0.f, ay = 0.f;
        if (wsum != 0.f) {
#pragma unroll
            for (int k = 0; k < 8; ++k) {
                const float2 v = *(const float2*)(ytn + (size_t)idx8[k] * 128 + 2 * lane);
                ax = fmaf(w8[k], v.x, ax);
                ay = fmaf(w8[k], v.y, ay);
            }
        }
        lds[(2 * lane) * 65 + pt] = ax;
        lds[(2 * lane + 1) * 65 + pt] = ay;
    }
    __syncthreads();
    // coalesced store: 128 channel-rows of 64 points
    const int pw = tid & 63, cw = tid >> 6;
    float* ob = out + (size_t)n * 128 * 65536 + p0 + pw;
#pragma unroll
    for (int k = 0; k < 32; ++k) {
        int c = k * 4 + cw;
        ob[(size_t)c * 65536] = lds[c * 65 + pw];
    }
}

extern "C" void kernel_launch(void* const* d_in, const int* in_sizes, int n_in,
                              void* d_out, int out_size, void* d_ws, size_t ws_size,
                              hipStream_t stream) {
    const float* x     = (const float*)d_in[0];
    const float* y     = (const float*)d_in[1];
    const float* wdh   = (const float*)d_in[2];
    const float* wdl   = (const float*)d_in[3];
    const float* wflow = (const float*)d_in[4];
    const float* watt  = (const float*)d_in[5];
    const float* wconv = (const float*)d_in[6];
    float* out = (float*)d_out;

    float* ws     = (float*)d_ws;
    float* meanx  = ws;                   // 128
    float* wcombT = meanx + 128;          // 8192
    float* hf     = wcombT + 8192;        // 1048576
    float* low2   = hf + 1048576;         // 8388608
    float* hfup   = low2 + 8388608;       // 8388608
    float* vg     = hfup + 8388608;       // 393216

    // partials live in d_out (16*2*3*65536 = 6.29M floats <= 16.77M);
    // fully written by kflowp before kcomb reads; ksample overwrites all of d_out.
    float* part = out;
    // yt (2.1M floats) reuses the hfup region — hfup is dead after kflowp.
    float* yt = hfup;

    kmean<<<128, 256, 0, stream>>>(x, meanx);
    kprep<<<2, 256, 0, stream>>>(wdl, watt, wconv, meanx, wcombT);
    kconv1l<<<512, 256, 0, stream>>>(x, wcombT, low2);
    kconvh<<<128, 256, 0, stream>>>(y, wdh, hf);
    kups<<<32768, 256, 0, stream>>>(hf, hfup);
    kflowp<<<1024, 256, 0, stream>>>(hfup, low2, wflow, part);
    kcomb<<<512, 256, 0, stream>>>(part, vg);
    ktrans<<<512, 256, 0, stream>>>(y, yt);      // after kflowp: hfup region now free
    ksample<<<2048, 256, 0, stream>>>(yt, vg, out);
}